// Round 5
// baseline (327.897 us; speedup 1.0000x reference)
//
#include <hip/hip_runtime.h>
#include <hip/hip_cooperative_groups.h>

namespace cg = cooperative_groups;

#define NN 50000
#define NE 625000
#define NB 49  // ceil(NN/1024)
#define CSR_BLOCKS 208

typedef __bf16 bf16_8 __attribute__((ext_vector_type(8)));
typedef __bf16 bf16_4 __attribute__((ext_vector_type(4)));
typedef float f32_4 __attribute__((ext_vector_type(4)));

// ---------------- K1: cooperative CSR build + weight convert ----------------
// Wl[K=128][NO], Wr[K=128][NO] fp32 -> Wt[2*NO][128] bf16 transposed concat

__device__ __forceinline__ void convw_one(const float* Wl, const float* Wr,
                                          __bf16* Wt, int NO, int i) {
    int k = i & 127;
    int n = i >> 7;
    const float* W = (n < NO) ? Wl : Wr;
    int nn = (n < NO) ? n : n - NO;
    Wt[i] = (__bf16)W[k * NO + nn];
}

__global__ __launch_bounds__(1024)
void csr_kernel(const int* __restrict__ src, const int* __restrict__ dst,
                int* __restrict__ deg, int* __restrict__ rowstart,
                int* __restrict__ cursor, int* __restrict__ col,
                float* __restrict__ inv, int* __restrict__ bsum, int* __restrict__ bbase,
                const float* __restrict__ Wl1, const float* __restrict__ Wr1, __bf16* __restrict__ Wt1,
                const float* __restrict__ Wl2, const float* __restrict__ Wr2, __bf16* __restrict__ Wt2,
                const float* __restrict__ Wl3, const float* __restrict__ Wr3, __bf16* __restrict__ Wt3) {
    cg::grid_group grid = cg::this_grid();
    __shared__ int s[1024];
    const int tid = threadIdx.x;
    const int b = blockIdx.x;
    const int g0 = b * 1024 + tid;
    const int gstride = CSR_BLOCKS * 1024;

    // P0: zero deg + convert weights
    for (int i = g0; i < NN; i += gstride) deg[i] = 0;
    for (int i = g0; i < 81920; i += gstride) {
        if (i < 32768)      convw_one(Wl1, Wr1, Wt1, 128, i);
        else if (i < 65536) convw_one(Wl2, Wr2, Wt2, 128, i - 32768);
        else                convw_one(Wl3, Wr3, Wt3, 64, i - 65536);
    }
    grid.sync();

    // P1: degree count
    for (int e = g0; e < NE; e += gstride) atomicAdd(&deg[dst[e]], 1);
    grid.sync();

    // P2: per-block inclusive scan (blocks 0..NB-1 cover all nodes)
    int v = 0, incl = 0;
    if (b < NB) {
        int i = b * 1024 + tid;
        v = (i < NN) ? deg[i] : 0;
        s[tid] = v;
        __syncthreads();
        for (int off = 1; off < 1024; off <<= 1) {
            int t = (tid >= off) ? s[tid - off] : 0;
            __syncthreads();
            s[tid] += t;
            __syncthreads();
        }
        incl = s[tid];
        if (tid == 1023) bsum[b] = s[1023];
    }
    grid.sync();

    // P3: scan of block sums (one wave of block 0)
    if (b == 0 && tid < 64) {
        int bv = (tid < NB) ? bsum[tid] : 0;
        int orig = bv;
        for (int off = 1; off < 64; off <<= 1) {
            int t = __shfl_up(bv, off, 64);
            if (tid >= off) bv += t;
        }
        if (tid < NB) bbase[tid] = bv - orig;
    }
    grid.sync();

    // P4: write rowstart / cursor / inv
    if (b < NB) {
        int i = b * 1024 + tid;
        if (i < NN) {
            int excl = bbase[b] + incl - v;
            rowstart[i] = excl;
            cursor[i] = excl;
            inv[i] = 1.0f / (float)max(v, 1);
        }
    }
    if (g0 == 0) rowstart[NN] = NE;
    grid.sync();

    // P5: CSR fill
    for (int e = g0; e < NE; e += gstride) {
        int p = atomicAdd(&cursor[dst[e]], 1);
        col[p] = src[e];
    }
}

// ---------------- bf16 MFMA GEMM ----------------
// A [M][128] (fp32 if AF32 else bf16), Bt [2*NO][128] bf16 (transposed concat Wl|Wr)
// cols 0..NO-1    -> Y bf16 [M][NO]      (lin_l path, no bias)
// cols NO..2NO-1  -> Z [M][NO] + bias    (lin_r path; bf16 or fp32 per ZF32)

template<int AF32, int ZF32>
__global__ __launch_bounds__(256)
void gemm_mfma(const void* __restrict__ Ap, const __bf16* __restrict__ Bt,
               const float* __restrict__ bias, __bf16* __restrict__ Y,
               void* __restrict__ Zp, int M, int NO) {
    __shared__ __bf16 As[128 * 128];
    __shared__ __bf16 Bs[128 * 128];
    const int t = threadIdx.x;
    const int m0 = blockIdx.x * 128;
    const int n0 = blockIdx.y * 128;

    #pragma unroll
    for (int it = 0; it < 8; ++it) {
        int r = (t >> 4) + it * 16;
        int c = t & 15;
        int cs = c ^ (r & 7);
        int gm = m0 + r;
        if (AF32) {
            const float* A32 = (const float*)Ap;
            float4 lo = make_float4(0.f, 0.f, 0.f, 0.f), hi = lo;
            if (gm < M) {
                lo = *(const float4*)&A32[(size_t)gm * 128 + c * 8];
                hi = *(const float4*)&A32[(size_t)gm * 128 + c * 8 + 4];
            }
            bf16_8 vv;
            vv[0] = (__bf16)lo.x; vv[1] = (__bf16)lo.y; vv[2] = (__bf16)lo.z; vv[3] = (__bf16)lo.w;
            vv[4] = (__bf16)hi.x; vv[5] = (__bf16)hi.y; vv[6] = (__bf16)hi.z; vv[7] = (__bf16)hi.w;
            *(bf16_8*)&As[r * 128 + cs * 8] = vv;
        } else {
            const __bf16* Ab = (const __bf16*)Ap;
            uint4 va = make_uint4(0, 0, 0, 0);
            if (gm < M) va = *(const uint4*)&Ab[(size_t)gm * 128 + c * 8];
            *(uint4*)&As[r * 128 + cs * 8] = va;
        }
        uint4 vb = *(const uint4*)&Bt[(size_t)(n0 + r) * 128 + c * 8];
        *(uint4*)&Bs[r * 128 + cs * 8] = vb;
    }
    __syncthreads();

    const int w = t >> 6;
    const int wm = (w >> 1) * 64;
    const int wn = (w & 1) * 64;
    const int lane = t & 63;
    const int lr = lane & 15;
    const int kg = lane >> 4;

    f32_4 acc[4][4] = {};
    #pragma unroll
    for (int ks = 0; ks < 4; ++ks) {
        int kc16 = ks * 4 + kg;
        bf16_8 a[4], bb[4];
        #pragma unroll
        for (int mi = 0; mi < 4; ++mi) {
            int r = wm + mi * 16 + lr;
            a[mi] = *(const bf16_8*)&As[r * 128 + (kc16 ^ (r & 7)) * 8];
        }
        #pragma unroll
        for (int ni = 0; ni < 4; ++ni) {
            int r = wn + ni * 16 + lr;
            bb[ni] = *(const bf16_8*)&Bs[r * 128 + (kc16 ^ (r & 7)) * 8];
        }
        #pragma unroll
        for (int mi = 0; mi < 4; ++mi)
            #pragma unroll
            for (int ni = 0; ni < 4; ++ni)
                acc[mi][ni] = __builtin_amdgcn_mfma_f32_16x16x32_bf16(a[mi], bb[ni], acc[mi][ni], 0, 0, 0);
    }

    #pragma unroll
    for (int mi = 0; mi < 4; ++mi) {
        int gmb = m0 + wm + mi * 16 + kg * 4;
        #pragma unroll
        for (int ni = 0; ni < 4; ++ni) {
            int gc = n0 + wn + ni * 16 + lr;
            bool isY = gc < NO;
            float bv = 0.f;
            if (!isY) bv = bias[gc - NO];
            #pragma unroll
            for (int rr = 0; rr < 4; ++rr) {
                int gm = gmb + rr;
                if (gm < M) {
                    float vv = acc[mi][ni][rr] + bv;
                    if (isY) Y[(size_t)gm * NO + gc] = (__bf16)vv;
                    else if (ZF32) ((float*)Zp)[(size_t)gm * NO + (gc - NO)] = vv;
                    else ((__bf16*)Zp)[(size_t)gm * NO + (gc - NO)] = (__bf16)vv;
                }
            }
        }
    }
}

// ---------------- aggregation: one 16-lane group per dst node, 8 rows in flight ----------------

__global__ __launch_bounds__(256)
void agg128_kernel(const __bf16* __restrict__ y, const __bf16* __restrict__ z,
                   const int* __restrict__ rowstart, const int* __restrict__ col,
                   const float* __restrict__ inv, __bf16* __restrict__ hout, int n) {
    int gid = blockIdx.x * 16 + (threadIdx.x >> 4);
    if (gid >= n) return;
    int s = threadIdx.x & 15;
    int beg = rowstart[gid], end = rowstart[gid + 1];
    float iv = inv[gid];
    float acc[8] = {};
    for (int e0 = beg; e0 < end; e0 += 8) {
        int us[8];
        #pragma unroll
        for (int k = 0; k < 8; ++k) us[k] = (e0 + k < end) ? col[e0 + k] : -1;
        bf16_8 vv[8];
        #pragma unroll
        for (int k = 0; k < 8; ++k) {
            vv[k] = (bf16_8){};
            if (us[k] >= 0) vv[k] = *(const bf16_8*)&y[(size_t)us[k] * 128 + s * 8];
        }
        #pragma unroll
        for (int j = 0; j < 8; ++j) {
            float p0 = ((float)vv[0][j] + (float)vv[1][j]) + ((float)vv[2][j] + (float)vv[3][j]);
            float p1 = ((float)vv[4][j] + (float)vv[5][j]) + ((float)vv[6][j] + (float)vv[7][j]);
            acc[j] += p0 + p1;
        }
    }
    bf16_8 zv = *(const bf16_8*)&z[(size_t)gid * 128 + s * 8];
    bf16_8 o;
    #pragma unroll
    for (int j = 0; j < 8; ++j) {
        float v = acc[j] * iv + (float)zv[j];
        o[j] = (__bf16)fmaxf(v, 0.f);
    }
    *(bf16_8*)&hout[(size_t)gid * 128 + s * 8] = o;
}

__global__ __launch_bounds__(256)
void agg64_kernel(const __bf16* __restrict__ y, const float* __restrict__ z,
                  const int* __restrict__ rowstart, const int* __restrict__ col,
                  const float* __restrict__ inv, float* __restrict__ fout, int n) {
    int gid = blockIdx.x * 16 + (threadIdx.x >> 4);
    if (gid >= n) return;
    int s = threadIdx.x & 15;
    int beg = rowstart[gid], end = rowstart[gid + 1];
    float iv = inv[gid];
    float acc[4] = {};
    for (int e0 = beg; e0 < end; e0 += 8) {
        int us[8];
        #pragma unroll
        for (int k = 0; k < 8; ++k) us[k] = (e0 + k < end) ? col[e0 + k] : -1;
        bf16_4 vv[8];
        #pragma unroll
        for (int k = 0; k < 8; ++k) {
            vv[k] = (bf16_4){};
            if (us[k] >= 0) vv[k] = *(const bf16_4*)&y[(size_t)us[k] * 64 + s * 4];
        }
        #pragma unroll
        for (int j = 0; j < 4; ++j) {
            float p0 = ((float)vv[0][j] + (float)vv[1][j]) + ((float)vv[2][j] + (float)vv[3][j]);
            float p1 = ((float)vv[4][j] + (float)vv[5][j]) + ((float)vv[6][j] + (float)vv[7][j]);
            acc[j] += p0 + p1;
        }
    }
    float4 zv = *(const float4*)&z[(size_t)gid * 64 + s * 4];
    float4 o;
    o.x = acc[0] * iv + zv.x;
    o.y = acc[1] * iv + zv.y;
    o.z = acc[2] * iv + zv.z;
    o.w = acc[3] * iv + zv.w;
    *(float4*)&fout[(size_t)gid * 64 + s * 4] = o;
}

// ---------------- launch ----------------

extern "C" void kernel_launch(void* const* d_in, const int* in_sizes, int n_in,
                              void* d_out, int out_size, void* d_ws, size_t ws_size,
                              hipStream_t stream) {
    const float* x   = (const float*)d_in[0];
    const int*   ei  = (const int*)d_in[1];
    const int*   src = ei;
    const int*   dst = ei + NE;
    const float* Wl1 = (const float*)d_in[2];
    const float* Wr1 = (const float*)d_in[3];
    const float* b1  = (const float*)d_in[4];
    const float* Wl2 = (const float*)d_in[5];
    const float* Wr2 = (const float*)d_in[6];
    const float* b2  = (const float*)d_in[7];
    const float* Wl3 = (const float*)d_in[8];
    const float* Wr3 = (const float*)d_in[9];
    const float* b3  = (const float*)d_in[10];
    float* out = (float*)d_out;

    char* ws = (char*)d_ws;
    size_t off = 0;
    auto alloc = [&](size_t bytes) -> void* {
        void* p = ws + off;
        off += (bytes + 255) & ~(size_t)255;
        return p;
    };

    int*    deg      = (int*)alloc(NN * 4);
    int*    rowstart = (int*)alloc((NN + 1) * 4);
    int*    cursor   = (int*)alloc(NN * 4);
    int*    col      = (int*)alloc(NE * 4);
    float*  inv      = (float*)alloc(NN * 4);
    int*    bsum     = (int*)alloc(NB * 4);
    int*    bbase    = (int*)alloc(NB * 4);
    __bf16* hb       = (__bf16*)alloc((size_t)NN * 128 * 2);
    __bf16* y        = (__bf16*)alloc((size_t)NN * 128 * 2);
    __bf16* zb       = (__bf16*)alloc((size_t)NN * 128 * 2);
    float*  zf       = (float*)alloc((size_t)NN * 64 * 4);
    __bf16* Wt1      = (__bf16*)alloc(256 * 128 * 2);
    __bf16* Wt2      = (__bf16*)alloc(256 * 128 * 2);
    __bf16* Wt3      = (__bf16*)alloc(128 * 128 * 2);

    {
        void* args[] = {
            (void*)&src, (void*)&dst, (void*)&deg, (void*)&rowstart, (void*)&cursor,
            (void*)&col, (void*)&inv, (void*)&bsum, (void*)&bbase,
            (void*)&Wl1, (void*)&Wr1, (void*)&Wt1,
            (void*)&Wl2, (void*)&Wr2, (void*)&Wt2,
            (void*)&Wl3, (void*)&Wr3, (void*)&Wt3,
        };
        hipLaunchCooperativeKernel((void*)csr_kernel, dim3(CSR_BLOCKS), dim3(1024),
                                   args, 0, stream);
    }

    int mblocks = (NN + 127) / 128;
    int aggBlocks = (NN + 15) / 16;

    // layer 1 (A = x fp32, Z bf16)
    gemm_mfma<1, 0><<<dim3(mblocks, 2), 256, 0, stream>>>(x, Wt1, b1, y, zb, NN, 128);
    agg128_kernel<<<aggBlocks, 256, 0, stream>>>(y, zb, rowstart, col, inv, hb, NN);
    // layer 2 (A = hb bf16, Z bf16)
    gemm_mfma<0, 0><<<dim3(mblocks, 2), 256, 0, stream>>>(hb, Wt2, b2, y, zb, NN, 128);
    agg128_kernel<<<aggBlocks, 256, 0, stream>>>(y, zb, rowstart, col, inv, hb, NN);
    // layer 3 (A = hb bf16, Z fp32)
    gemm_mfma<0, 1><<<dim3(mblocks, 1), 256, 0, stream>>>(hb, Wt3, b3, y, zf, NN, 64);
    agg64_kernel<<<aggBlocks, 256, 0, stream>>>(y, zf, rowstart, col, inv, out, NN);
}

// Round 6
// 218.752 us; speedup vs baseline: 1.4989x; 1.4989x over previous
//
#include <hip/hip_runtime.h>

#define NN 50000
#define NE 625000
#define NB 49  // ceil(NN/1024)

typedef __bf16 bf16_8 __attribute__((ext_vector_type(8)));
typedef __bf16 bf16_4 __attribute__((ext_vector_type(4)));
typedef float f32_4 __attribute__((ext_vector_type(4)));

// ---------------- K1: zero counters + convert all weights ----------------
// Wl[K=128][NO], Wr[K=128][NO] fp32 -> Wt[2*NO][128] bf16 transposed concat

__device__ __forceinline__ void convw_one(const float* Wl, const float* Wr,
                                          __bf16* Wt, int NO, int i) {
    int k = i & 127;
    int n = i >> 7;
    const float* W = (n < NO) ? Wl : Wr;
    int nn = (n < NO) ? n : n - NO;
    Wt[i] = (__bf16)W[k * NO + nn];
}

__global__ void init_kernel(int* __restrict__ deg, unsigned long long* __restrict__ state,
                            int* __restrict__ vcounter, int* __restrict__ rowstart,
                            const float* __restrict__ Wl1, const float* __restrict__ Wr1, __bf16* __restrict__ Wt1,
                            const float* __restrict__ Wl2, const float* __restrict__ Wr2, __bf16* __restrict__ Wt2,
                            const float* __restrict__ Wl3, const float* __restrict__ Wr3, __bf16* __restrict__ Wt3) {
    int i = blockIdx.x * blockDim.x + threadIdx.x;
    if (i < NN) deg[i] = 0;
    if (i < NB) state[i] = 0ull;
    if (i == 0) { *vcounter = 0; rowstart[NN] = NE; }
    if (i < 32768)      convw_one(Wl1, Wr1, Wt1, 128, i);
    else if (i < 65536) convw_one(Wl2, Wr2, Wt2, 128, i - 32768);
    else if (i < 81920) convw_one(Wl3, Wr3, Wt3, 64, i - 65536);
}

// ---------------- K2: degree count ----------------

__global__ void deg_kernel(const int* __restrict__ dst, int* __restrict__ deg, int e) {
    int i = blockIdx.x * blockDim.x + threadIdx.x;
    if (i < e) atomicAdd(&deg[dst[i]], 1);
}

// ---------------- K3: single-pass decoupled-lookback scan ----------------

__global__ __launch_bounds__(1024)
void scan_kernel(const int* __restrict__ deg, int* __restrict__ rowstart,
                 int* __restrict__ cursor, float* __restrict__ inv,
                 unsigned long long* __restrict__ state, int* __restrict__ vcounter) {
    __shared__ int s[1024];
    __shared__ int s_vb, s_base;
    int tid = threadIdx.x;
    if (tid == 0) s_vb = atomicAdd(vcounter, 1);
    __syncthreads();
    int vb = s_vb;
    int i = vb * 1024 + tid;
    int v = (i < NN) ? deg[i] : 0;
    s[tid] = v;
    __syncthreads();
    for (int off = 1; off < 1024; off <<= 1) {
        int t = (tid >= off) ? s[tid - off] : 0;
        __syncthreads();
        s[tid] += t;
        __syncthreads();
    }
    int incl = s[tid];
    int agg = s[1023];
    if (tid == 0) {
        if (vb == 0) {
            atomicExch(&state[0], (2ull << 62) | (unsigned long long)(unsigned)agg);
            s_base = 0;
        } else {
            atomicExch(&state[vb], (1ull << 62) | (unsigned long long)(unsigned)agg);
            int base = 0;
            int p = vb - 1;
            while (p >= 0) {
                unsigned long long st;
                do { st = atomicAdd(&state[p], 0ull); } while ((st >> 62) == 0ull);
                base += (int)(unsigned)(st & 0xffffffffull);
                if ((st >> 62) == 2ull) break;
                --p;
            }
            atomicExch(&state[vb], (2ull << 62) | (unsigned long long)(unsigned)(base + agg));
            s_base = base;
        }
    }
    __syncthreads();
    int base = s_base;
    if (i < NN) {
        int excl = base + incl - v;
        rowstart[i] = excl;
        cursor[i] = excl;
        inv[i] = 1.0f / (float)max(v, 1);
    }
}

// ---------------- K4: CSR fill ----------------

__global__ void fill_kernel(const int* __restrict__ src, const int* __restrict__ dst,
                            int* __restrict__ cursor, int* __restrict__ col, int e) {
    int i = blockIdx.x * blockDim.x + threadIdx.x;
    if (i < e) {
        int p = atomicAdd(&cursor[dst[i]], 1);
        col[p] = src[i];
    }
}

// ---------------- bf16 MFMA GEMM ----------------
// A [M][128] (fp32 if AF32 else bf16), Bt [2*NO][128] bf16 (transposed concat Wl|Wr)
// cols 0..NO-1    -> Y bf16 [M][NO]      (lin_l path, no bias)
// cols NO..2NO-1  -> Z [M][NO] + bias    (lin_r path; bf16 or fp32 per ZF32)

template<int AF32, int ZF32>
__global__ __launch_bounds__(256)
void gemm_mfma(const void* __restrict__ Ap, const __bf16* __restrict__ Bt,
               const float* __restrict__ bias, __bf16* __restrict__ Y,
               void* __restrict__ Zp, int M, int NO) {
    __shared__ __bf16 As[128 * 128];
    __shared__ __bf16 Bs[128 * 128];
    const int t = threadIdx.x;
    const int m0 = blockIdx.x * 128;
    const int n0 = blockIdx.y * 128;

    #pragma unroll
    for (int it = 0; it < 8; ++it) {
        int r = (t >> 4) + it * 16;
        int c = t & 15;
        int cs = c ^ (r & 7);
        int gm = m0 + r;
        if (AF32) {
            const float* A32 = (const float*)Ap;
            float4 lo = make_float4(0.f, 0.f, 0.f, 0.f), hi = lo;
            if (gm < M) {
                lo = *(const float4*)&A32[(size_t)gm * 128 + c * 8];
                hi = *(const float4*)&A32[(size_t)gm * 128 + c * 8 + 4];
            }
            bf16_8 vv;
            vv[0] = (__bf16)lo.x; vv[1] = (__bf16)lo.y; vv[2] = (__bf16)lo.z; vv[3] = (__bf16)lo.w;
            vv[4] = (__bf16)hi.x; vv[5] = (__bf16)hi.y; vv[6] = (__bf16)hi.z; vv[7] = (__bf16)hi.w;
            *(bf16_8*)&As[r * 128 + cs * 8] = vv;
        } else {
            const __bf16* Ab = (const __bf16*)Ap;
            uint4 va = make_uint4(0, 0, 0, 0);
            if (gm < M) va = *(const uint4*)&Ab[(size_t)gm * 128 + c * 8];
            *(uint4*)&As[r * 128 + cs * 8] = va;
        }
        uint4 vb = *(const uint4*)&Bt[(size_t)(n0 + r) * 128 + c * 8];
        *(uint4*)&Bs[r * 128 + cs * 8] = vb;
    }
    __syncthreads();

    const int w = t >> 6;
    const int wm = (w >> 1) * 64;
    const int wn = (w & 1) * 64;
    const int lane = t & 63;
    const int lr = lane & 15;
    const int kg = lane >> 4;

    f32_4 acc[4][4] = {};
    #pragma unroll
    for (int ks = 0; ks < 4; ++ks) {
        int kc16 = ks * 4 + kg;
        bf16_8 a[4], bb[4];
        #pragma unroll
        for (int mi = 0; mi < 4; ++mi) {
            int r = wm + mi * 16 + lr;
            a[mi] = *(const bf16_8*)&As[r * 128 + (kc16 ^ (r & 7)) * 8];
        }
        #pragma unroll
        for (int ni = 0; ni < 4; ++ni) {
            int r = wn + ni * 16 + lr;
            bb[ni] = *(const bf16_8*)&Bs[r * 128 + (kc16 ^ (r & 7)) * 8];
        }
        #pragma unroll
        for (int mi = 0; mi < 4; ++mi)
            #pragma unroll
            for (int ni = 0; ni < 4; ++ni)
                acc[mi][ni] = __builtin_amdgcn_mfma_f32_16x16x32_bf16(a[mi], bb[ni], acc[mi][ni], 0, 0, 0);
    }

    #pragma unroll
    for (int mi = 0; mi < 4; ++mi) {
        int gmb = m0 + wm + mi * 16 + kg * 4;
        #pragma unroll
        for (int ni = 0; ni < 4; ++ni) {
            int gc = n0 + wn + ni * 16 + lr;
            bool isY = gc < NO;
            float bv = 0.f;
            if (!isY) bv = bias[gc - NO];
            #pragma unroll
            for (int rr = 0; rr < 4; ++rr) {
                int gm = gmb + rr;
                if (gm < M) {
                    float vv = acc[mi][ni][rr] + bv;
                    if (isY) Y[(size_t)gm * NO + gc] = (__bf16)vv;
                    else if (ZF32) ((float*)Zp)[(size_t)gm * NO + (gc - NO)] = vv;
                    else ((__bf16*)Zp)[(size_t)gm * NO + (gc - NO)] = (__bf16)vv;
                }
            }
        }
    }
}

// ---------------- aggregation: one 16-lane group per dst node, 8 rows in flight ----------------

__global__ __launch_bounds__(256)
void agg128_kernel(const __bf16* __restrict__ y, const __bf16* __restrict__ z,
                   const int* __restrict__ rowstart, const int* __restrict__ col,
                   const float* __restrict__ inv, __bf16* __restrict__ hout, int n) {
    int gid = blockIdx.x * 16 + (threadIdx.x >> 4);
    if (gid >= n) return;
    int s = threadIdx.x & 15;
    int beg = rowstart[gid], end = rowstart[gid + 1];
    float iv = inv[gid];
    float acc[8] = {};
    for (int e0 = beg; e0 < end; e0 += 8) {
        int us[8];
        #pragma unroll
        for (int k = 0; k < 8; ++k) us[k] = (e0 + k < end) ? col[e0 + k] : -1;
        bf16_8 vv[8];
        #pragma unroll
        for (int k = 0; k < 8; ++k) {
            vv[k] = (bf16_8){};
            if (us[k] >= 0) vv[k] = *(const bf16_8*)&y[(size_t)us[k] * 128 + s * 8];
        }
        #pragma unroll
        for (int j = 0; j < 8; ++j) {
            float p0 = ((float)vv[0][j] + (float)vv[1][j]) + ((float)vv[2][j] + (float)vv[3][j]);
            float p1 = ((float)vv[4][j] + (float)vv[5][j]) + ((float)vv[6][j] + (float)vv[7][j]);
            acc[j] += p0 + p1;
        }
    }
    bf16_8 zv = *(const bf16_8*)&z[(size_t)gid * 128 + s * 8];
    bf16_8 o;
    #pragma unroll
    for (int j = 0; j < 8; ++j) {
        float v = acc[j] * iv + (float)zv[j];
        o[j] = (__bf16)fmaxf(v, 0.f);
    }
    *(bf16_8*)&hout[(size_t)gid * 128 + s * 8] = o;
}

__global__ __launch_bounds__(256)
void agg64_kernel(const __bf16* __restrict__ y, const float* __restrict__ z,
                  const int* __restrict__ rowstart, const int* __restrict__ col,
                  const float* __restrict__ inv, float* __restrict__ fout, int n) {
    int gid = blockIdx.x * 16 + (threadIdx.x >> 4);
    if (gid >= n) return;
    int s = threadIdx.x & 15;
    int beg = rowstart[gid], end = rowstart[gid + 1];
    float iv = inv[gid];
    float acc[4] = {};
    for (int e0 = beg; e0 < end; e0 += 8) {
        int us[8];
        #pragma unroll
        for (int k = 0; k < 8; ++k) us[k] = (e0 + k < end) ? col[e0 + k] : -1;
        bf16_4 vv[8];
        #pragma unroll
        for (int k = 0; k < 8; ++k) {
            vv[k] = (bf16_4){};
            if (us[k] >= 0) vv[k] = *(const bf16_4*)&y[(size_t)us[k] * 64 + s * 4];
        }
        #pragma unroll
        for (int j = 0; j < 4; ++j) {
            float p0 = ((float)vv[0][j] + (float)vv[1][j]) + ((float)vv[2][j] + (float)vv[3][j]);
            float p1 = ((float)vv[4][j] + (float)vv[5][j]) + ((float)vv[6][j] + (float)vv[7][j]);
            acc[j] += p0 + p1;
        }
    }
    float4 zv = *(const float4*)&z[(size_t)gid * 64 + s * 4];
    float4 o;
    o.x = acc[0] * iv + zv.x;
    o.y = acc[1] * iv + zv.y;
    o.z = acc[2] * iv + zv.z;
    o.w = acc[3] * iv + zv.w;
    *(float4*)&fout[(size_t)gid * 64 + s * 4] = o;
}

// ---------------- launch ----------------

extern "C" void kernel_launch(void* const* d_in, const int* in_sizes, int n_in,
                              void* d_out, int out_size, void* d_ws, size_t ws_size,
                              hipStream_t stream) {
    const float* x   = (const float*)d_in[0];
    const int*   ei  = (const int*)d_in[1];
    const int*   src = ei;
    const int*   dst = ei + NE;
    const float* Wl1 = (const float*)d_in[2];
    const float* Wr1 = (const float*)d_in[3];
    const float* b1  = (const float*)d_in[4];
    const float* Wl2 = (const float*)d_in[5];
    const float* Wr2 = (const float*)d_in[6];
    const float* b2  = (const float*)d_in[7];
    const float* Wl3 = (const float*)d_in[8];
    const float* Wr3 = (const float*)d_in[9];
    const float* b3  = (const float*)d_in[10];
    float* out = (float*)d_out;

    char* ws = (char*)d_ws;
    size_t off = 0;
    auto alloc = [&](size_t bytes) -> void* {
        void* p = ws + off;
        off += (bytes + 255) & ~(size_t)255;
        return p;
    };

    int*    deg      = (int*)alloc(NN * 4);
    int*    rowstart = (int*)alloc((NN + 1) * 4);
    int*    cursor   = (int*)alloc(NN * 4);
    int*    col      = (int*)alloc(NE * 4);
    float*  inv      = (float*)alloc(NN * 4);
    unsigned long long* state = (unsigned long long*)alloc(NB * 8);
    int*    vcounter = (int*)alloc(4);
    __bf16* hb       = (__bf16*)alloc((size_t)NN * 128 * 2);
    __bf16* y        = (__bf16*)alloc((size_t)NN * 128 * 2);
    __bf16* zb       = (__bf16*)alloc((size_t)NN * 128 * 2);
    float*  zf       = (float*)alloc((size_t)NN * 64 * 4);
    __bf16* Wt1      = (__bf16*)alloc(256 * 128 * 2);
    __bf16* Wt2      = (__bf16*)alloc(256 * 128 * 2);
    __bf16* Wt3      = (__bf16*)alloc(128 * 128 * 2);

    init_kernel<<<320, 256, 0, stream>>>(deg, state, vcounter, rowstart,
                                         Wl1, Wr1, Wt1, Wl2, Wr2, Wt2, Wl3, Wr3, Wt3);
    deg_kernel<<<(NE + 255) / 256, 256, 0, stream>>>(dst, deg, NE);
    scan_kernel<<<NB, 1024, 0, stream>>>(deg, rowstart, cursor, inv, state, vcounter);
    fill_kernel<<<(NE + 255) / 256, 256, 0, stream>>>(src, dst, cursor, col, NE);

    int mblocks = (NN + 127) / 128;
    int aggBlocks = (NN + 15) / 16;

    // layer 1 (A = x fp32, Z bf16)
    gemm_mfma<1, 0><<<dim3(mblocks, 2), 256, 0, stream>>>(x, Wt1, b1, y, zb, NN, 128);
    agg128_kernel<<<aggBlocks, 256, 0, stream>>>(y, zb, rowstart, col, inv, hb, NN);
    // layer 2 (A = hb bf16, Z bf16)
    gemm_mfma<0, 0><<<dim3(mblocks, 2), 256, 0, stream>>>(hb, Wt2, b2, y, zb, NN, 128);
    agg128_kernel<<<aggBlocks, 256, 0, stream>>>(y, zb, rowstart, col, inv, hb, NN);
    // layer 3 (A = hb bf16, Z fp32)
    gemm_mfma<0, 1><<<dim3(mblocks, 1), 256, 0, stream>>>(hb, Wt3, b3, y, zf, NN, 64);
    agg64_kernel<<<aggBlocks, 256, 0, stream>>>(y, zf, rowstart, col, inv, out, NN);
}

// Round 7
// 215.426 us; speedup vs baseline: 1.5221x; 1.0154x over previous
//
#include <hip/hip_runtime.h>
#include <hip/hip_fp8.h>

#define NN 50000
#define NE 625000
#define NB 49  // ceil(NN/1024)

typedef __bf16 bf16_8 __attribute__((ext_vector_type(8)));
typedef __bf16 bf16_4 __attribute__((ext_vector_type(4)));
typedef float f32_4 __attribute__((ext_vector_type(4)));

__device__ __forceinline__ unsigned char f32_to_e4m3(float v) {
    __hip_fp8_e4m3 t(v);
    union { __hip_fp8_e4m3 t; unsigned char b; } u;
    u.t = t;
    return u.b;
}

__device__ __forceinline__ float e4m3_to_f32(unsigned char b) {
    union { unsigned char b; __hip_fp8_e4m3 t; } u;
    u.b = b;
    return (float)u.t;
}

// ---------------- K1: zero counters + convert all weights ----------------
// Wl[K=128][NO], Wr[K=128][NO] fp32 -> Wt[2*NO][128] bf16 transposed concat

__device__ __forceinline__ void convw_one(const float* Wl, const float* Wr,
                                          __bf16* Wt, int NO, int i) {
    int k = i & 127;
    int n = i >> 7;
    const float* W = (n < NO) ? Wl : Wr;
    int nn = (n < NO) ? n : n - NO;
    Wt[i] = (__bf16)W[k * NO + nn];
}

__global__ void init_kernel(int* __restrict__ deg, unsigned long long* __restrict__ state,
                            int* __restrict__ vcounter, int* __restrict__ rowstart,
                            const float* __restrict__ Wl1, const float* __restrict__ Wr1, __bf16* __restrict__ Wt1,
                            const float* __restrict__ Wl2, const float* __restrict__ Wr2, __bf16* __restrict__ Wt2,
                            const float* __restrict__ Wl3, const float* __restrict__ Wr3, __bf16* __restrict__ Wt3) {
    int i = blockIdx.x * blockDim.x + threadIdx.x;
    if (i < NN) deg[i] = 0;
    if (i < NB) state[i] = 0ull;
    if (i == 0) { *vcounter = 0; rowstart[NN] = NE; }
    if (i < 32768)      convw_one(Wl1, Wr1, Wt1, 128, i);
    else if (i < 65536) convw_one(Wl2, Wr2, Wt2, 128, i - 32768);
    else if (i < 81920) convw_one(Wl3, Wr3, Wt3, 64, i - 65536);
}

// ---------------- K2: degree count ----------------

__global__ void deg_kernel(const int* __restrict__ dst, int* __restrict__ deg, int e) {
    int i = blockIdx.x * blockDim.x + threadIdx.x;
    if (i < e) atomicAdd(&deg[dst[i]], 1);
}

// ---------------- K3: single-pass decoupled-lookback scan ----------------

__global__ __launch_bounds__(1024)
void scan_kernel(const int* __restrict__ deg, int* __restrict__ rowstart,
                 int* __restrict__ cursor, float* __restrict__ inv,
                 unsigned long long* __restrict__ state, int* __restrict__ vcounter) {
    __shared__ int s[1024];
    __shared__ int s_vb, s_base;
    int tid = threadIdx.x;
    if (tid == 0) s_vb = atomicAdd(vcounter, 1);
    __syncthreads();
    int vb = s_vb;
    int i = vb * 1024 + tid;
    int v = (i < NN) ? deg[i] : 0;
    s[tid] = v;
    __syncthreads();
    for (int off = 1; off < 1024; off <<= 1) {
        int t = (tid >= off) ? s[tid - off] : 0;
        __syncthreads();
        s[tid] += t;
        __syncthreads();
    }
    int incl = s[tid];
    int agg = s[1023];
    if (tid == 0) {
        if (vb == 0) {
            atomicExch(&state[0], (2ull << 62) | (unsigned long long)(unsigned)agg);
            s_base = 0;
        } else {
            atomicExch(&state[vb], (1ull << 62) | (unsigned long long)(unsigned)agg);
            int base = 0;
            int p = vb - 1;
            while (p >= 0) {
                unsigned long long st;
                do { st = atomicAdd(&state[p], 0ull); } while ((st >> 62) == 0ull);
                base += (int)(unsigned)(st & 0xffffffffull);
                if ((st >> 62) == 2ull) break;
                --p;
            }
            atomicExch(&state[vb], (2ull << 62) | (unsigned long long)(unsigned)(base + agg));
            s_base = base;
        }
    }
    __syncthreads();
    int base = s_base;
    if (i < NN) {
        int excl = base + incl - v;
        rowstart[i] = excl;
        cursor[i] = excl;
        inv[i] = 1.0f / (float)max(v, 1);
    }
}

// ---------------- K4: CSR fill ----------------

__global__ void fill_kernel(const int* __restrict__ src, const int* __restrict__ dst,
                            int* __restrict__ cursor, int* __restrict__ col, int e) {
    int i = blockIdx.x * blockDim.x + threadIdx.x;
    if (i < e) {
        int p = atomicAdd(&cursor[dst[i]], 1);
        col[p] = src[i];
    }
}

// ---------------- bf16 MFMA GEMM ----------------
// A [M][128] (fp32 if AF32 else bf16), Bt [2*NO][128] bf16 (transposed concat Wl|Wr)
// cols 0..NO-1    -> Y [M][NO]           (lin_l path, no bias; fp8 if YF8 else bf16)
// cols NO..2NO-1  -> Z [M][NO] + bias    (lin_r path; fp32 if ZF32 else bf16)

template<int AF32, int ZF32, int YF8>
__global__ __launch_bounds__(256)
void gemm_mfma(const void* __restrict__ Ap, const __bf16* __restrict__ Bt,
               const float* __restrict__ bias, void* __restrict__ Yp,
               void* __restrict__ Zp, int M, int NO) {
    __shared__ __bf16 As[128 * 128];
    __shared__ __bf16 Bs[128 * 128];
    const int t = threadIdx.x;
    const int m0 = blockIdx.x * 128;
    const int n0 = blockIdx.y * 128;

    #pragma unroll
    for (int it = 0; it < 8; ++it) {
        int r = (t >> 4) + it * 16;
        int c = t & 15;
        int cs = c ^ (r & 7);
        int gm = m0 + r;
        if (AF32) {
            const float* A32 = (const float*)Ap;
            float4 lo = make_float4(0.f, 0.f, 0.f, 0.f), hi = lo;
            if (gm < M) {
                lo = *(const float4*)&A32[(size_t)gm * 128 + c * 8];
                hi = *(const float4*)&A32[(size_t)gm * 128 + c * 8 + 4];
            }
            bf16_8 vv;
            vv[0] = (__bf16)lo.x; vv[1] = (__bf16)lo.y; vv[2] = (__bf16)lo.z; vv[3] = (__bf16)lo.w;
            vv[4] = (__bf16)hi.x; vv[5] = (__bf16)hi.y; vv[6] = (__bf16)hi.z; vv[7] = (__bf16)hi.w;
            *(bf16_8*)&As[r * 128 + cs * 8] = vv;
        } else {
            const __bf16* Ab = (const __bf16*)Ap;
            uint4 va = make_uint4(0, 0, 0, 0);
            if (gm < M) va = *(const uint4*)&Ab[(size_t)gm * 128 + c * 8];
            *(uint4*)&As[r * 128 + cs * 8] = va;
        }
        uint4 vb = *(const uint4*)&Bt[(size_t)(n0 + r) * 128 + c * 8];
        *(uint4*)&Bs[r * 128 + cs * 8] = vb;
    }
    __syncthreads();

    const int w = t >> 6;
    const int wm = (w >> 1) * 64;
    const int wn = (w & 1) * 64;
    const int lane = t & 63;
    const int lr = lane & 15;
    const int kg = lane >> 4;

    f32_4 acc[4][4] = {};
    #pragma unroll
    for (int ks = 0; ks < 4; ++ks) {
        int kc16 = ks * 4 + kg;
        bf16_8 a[4], bb[4];
        #pragma unroll
        for (int mi = 0; mi < 4; ++mi) {
            int r = wm + mi * 16 + lr;
            a[mi] = *(const bf16_8*)&As[r * 128 + (kc16 ^ (r & 7)) * 8];
        }
        #pragma unroll
        for (int ni = 0; ni < 4; ++ni) {
            int r = wn + ni * 16 + lr;
            bb[ni] = *(const bf16_8*)&Bs[r * 128 + (kc16 ^ (r & 7)) * 8];
        }
        #pragma unroll
        for (int mi = 0; mi < 4; ++mi)
            #pragma unroll
            for (int ni = 0; ni < 4; ++ni)
                acc[mi][ni] = __builtin_amdgcn_mfma_f32_16x16x32_bf16(a[mi], bb[ni], acc[mi][ni], 0, 0, 0);
    }

    #pragma unroll
    for (int mi = 0; mi < 4; ++mi) {
        int gmb = m0 + wm + mi * 16 + kg * 4;
        #pragma unroll
        for (int ni = 0; ni < 4; ++ni) {
            int gc = n0 + wn + ni * 16 + lr;
            bool isY = gc < NO;
            float bv = 0.f;
            if (!isY) bv = bias[gc - NO];
            #pragma unroll
            for (int rr = 0; rr < 4; ++rr) {
                int gm = gmb + rr;
                if (gm < M) {
                    float vv = acc[mi][ni][rr] + bv;
                    if (isY) {
                        if (YF8) ((unsigned char*)Yp)[(size_t)gm * NO + gc] = f32_to_e4m3(vv);
                        else     ((__bf16*)Yp)[(size_t)gm * NO + gc] = (__bf16)vv;
                    }
                    else if (ZF32) ((float*)Zp)[(size_t)gm * NO + (gc - NO)] = vv;
                    else ((__bf16*)Zp)[(size_t)gm * NO + (gc - NO)] = (__bf16)vv;
                }
            }
        }
    }
}

// ---------------- aggregation ----------------
// one 16-lane group per dst node, 8 rows in flight
// layers 1-2: y is fp8 e4m3 [node][128] (128B row = 1 cache line)

__global__ __launch_bounds__(256)
void agg128f8_kernel(const unsigned char* __restrict__ y8, const __bf16* __restrict__ z,
                     const int* __restrict__ rowstart, const int* __restrict__ col,
                     const float* __restrict__ inv, __bf16* __restrict__ hout, int n) {
    int gid = blockIdx.x * 16 + (threadIdx.x >> 4);
    if (gid >= n) return;
    int s = threadIdx.x & 15;
    int beg = rowstart[gid], end = rowstart[gid + 1];
    float iv = inv[gid];
    float acc[8] = {};
    for (int e0 = beg; e0 < end; e0 += 8) {
        int us[8];
        #pragma unroll
        for (int k = 0; k < 8; ++k) us[k] = (e0 + k < end) ? col[e0 + k] : -1;
        uint2 vv[8];
        #pragma unroll
        for (int k = 0; k < 8; ++k) {
            vv[k] = make_uint2(0u, 0u);  // fp8 0x00 decodes to 0.0f
            if (us[k] >= 0) vv[k] = *(const uint2*)&y8[(size_t)us[k] * 128 + s * 8];
        }
        #pragma unroll
        for (int k = 0; k < 8; ++k) {
            unsigned int lo = vv[k].x, hi = vv[k].y;
            acc[0] += e4m3_to_f32((lo) & 0xff);
            acc[1] += e4m3_to_f32((lo >> 8) & 0xff);
            acc[2] += e4m3_to_f32((lo >> 16) & 0xff);
            acc[3] += e4m3_to_f32((lo >> 24) & 0xff);
            acc[4] += e4m3_to_f32((hi) & 0xff);
            acc[5] += e4m3_to_f32((hi >> 8) & 0xff);
            acc[6] += e4m3_to_f32((hi >> 16) & 0xff);
            acc[7] += e4m3_to_f32((hi >> 24) & 0xff);
        }
    }
    bf16_8 zv = *(const bf16_8*)&z[(size_t)gid * 128 + s * 8];
    bf16_8 o;
    #pragma unroll
    for (int j = 0; j < 8; ++j) {
        float v = acc[j] * iv + (float)zv[j];
        o[j] = (__bf16)fmaxf(v, 0.f);
    }
    *(bf16_8*)&hout[(size_t)gid * 128 + s * 8] = o;
}

__global__ __launch_bounds__(256)
void agg64_kernel(const __bf16* __restrict__ y, const float* __restrict__ z,
                  const int* __restrict__ rowstart, const int* __restrict__ col,
                  const float* __restrict__ inv, float* __restrict__ fout, int n) {
    int gid = blockIdx.x * 16 + (threadIdx.x >> 4);
    if (gid >= n) return;
    int s = threadIdx.x & 15;
    int beg = rowstart[gid], end = rowstart[gid + 1];
    float iv = inv[gid];
    float acc[4] = {};
    for (int e0 = beg; e0 < end; e0 += 8) {
        int us[8];
        #pragma unroll
        for (int k = 0; k < 8; ++k) us[k] = (e0 + k < end) ? col[e0 + k] : -1;
        bf16_4 vv[8];
        #pragma unroll
        for (int k = 0; k < 8; ++k) {
            vv[k] = (bf16_4){};
            if (us[k] >= 0) vv[k] = *(const bf16_4*)&y[(size_t)us[k] * 64 + s * 4];
        }
        #pragma unroll
        for (int j = 0; j < 4; ++j) {
            float p0 = ((float)vv[0][j] + (float)vv[1][j]) + ((float)vv[2][j] + (float)vv[3][j]);
            float p1 = ((float)vv[4][j] + (float)vv[5][j]) + ((float)vv[6][j] + (float)vv[7][j]);
            acc[j] += p0 + p1;
        }
    }
    float4 zv = *(const float4*)&z[(size_t)gid * 64 + s * 4];
    float4 o;
    o.x = acc[0] * iv + zv.x;
    o.y = acc[1] * iv + zv.y;
    o.z = acc[2] * iv + zv.z;
    o.w = acc[3] * iv + zv.w;
    *(float4*)&fout[(size_t)gid * 64 + s * 4] = o;
}

// ---------------- launch ----------------

extern "C" void kernel_launch(void* const* d_in, const int* in_sizes, int n_in,
                              void* d_out, int out_size, void* d_ws, size_t ws_size,
                              hipStream_t stream) {
    const float* x   = (const float*)d_in[0];
    const int*   ei  = (const int*)d_in[1];
    const int*   src = ei;
    const int*   dst = ei + NE;
    const float* Wl1 = (const float*)d_in[2];
    const float* Wr1 = (const float*)d_in[3];
    const float* b1  = (const float*)d_in[4];
    const float* Wl2 = (const float*)d_in[5];
    const float* Wr2 = (const float*)d_in[6];
    const float* b2  = (const float*)d_in[7];
    const float* Wl3 = (const float*)d_in[8];
    const float* Wr3 = (const float*)d_in[9];
    const float* b3  = (const float*)d_in[10];
    float* out = (float*)d_out;

    char* ws = (char*)d_ws;
    size_t off = 0;
    auto alloc = [&](size_t bytes) -> void* {
        void* p = ws + off;
        off += (bytes + 255) & ~(size_t)255;
        return p;
    };

    int*    deg      = (int*)alloc(NN * 4);
    int*    rowstart = (int*)alloc((NN + 1) * 4);
    int*    cursor   = (int*)alloc(NN * 4);
    int*    col      = (int*)alloc(NE * 4);
    float*  inv      = (float*)alloc(NN * 4);
    unsigned long long* state = (unsigned long long*)alloc(NB * 8);
    int*    vcounter = (int*)alloc(4);
    __bf16* hb       = (__bf16*)alloc((size_t)NN * 128 * 2);
    unsigned char* y8 = (unsigned char*)alloc((size_t)NN * 128);
    __bf16* y        = (__bf16*)alloc((size_t)NN * 64 * 2);
    __bf16* zb       = (__bf16*)alloc((size_t)NN * 128 * 2);
    float*  zf       = (float*)alloc((size_t)NN * 64 * 4);
    __bf16* Wt1      = (__bf16*)alloc(256 * 128 * 2);
    __bf16* Wt2      = (__bf16*)alloc(256 * 128 * 2);
    __bf16* Wt3      = (__bf16*)alloc(128 * 128 * 2);

    init_kernel<<<320, 256, 0, stream>>>(deg, state, vcounter, rowstart,
                                         Wl1, Wr1, Wt1, Wl2, Wr2, Wt2, Wl3, Wr3, Wt3);
    deg_kernel<<<(NE + 255) / 256, 256, 0, stream>>>(dst, deg, NE);
    scan_kernel<<<NB, 1024, 0, stream>>>(deg, rowstart, cursor, inv, state, vcounter);
    fill_kernel<<<(NE + 255) / 256, 256, 0, stream>>>(src, dst, cursor, col, NE);

    int mblocks = (NN + 127) / 128;
    int aggBlocks = (NN + 15) / 16;

    // layer 1 (A = x fp32, Y fp8, Z bf16)
    gemm_mfma<1, 0, 1><<<dim3(mblocks, 2), 256, 0, stream>>>(x, Wt1, b1, y8, zb, NN, 128);
    agg128f8_kernel<<<aggBlocks, 256, 0, stream>>>(y8, zb, rowstart, col, inv, hb, NN);
    // layer 2 (A = hb bf16, Y fp8, Z bf16)
    gemm_mfma<0, 0, 1><<<dim3(mblocks, 2), 256, 0, stream>>>(hb, Wt2, b2, y8, zb, NN, 128);
    agg128f8_kernel<<<aggBlocks, 256, 0, stream>>>(y8, zb, rowstart, col, inv, hb, NN);
    // layer 3 (A = hb bf16, Y bf16, Z fp32)
    gemm_mfma<0, 1, 0><<<dim3(mblocks, 1), 256, 0, stream>>>(hb, Wt3, b3, y, zf, NN, 64);
    agg64_kernel<<<aggBlocks, 256, 0, stream>>>(y, zf, rowstart, col, inv, out, NN);
}

// Round 8
// 196.934 us; speedup vs baseline: 1.6650x; 1.0939x over previous
//
#include <hip/hip_runtime.h>

#define NN 50000
#define NE 625000
#define NB 49  // ceil(NN/1024)

typedef __bf16 bf16_8 __attribute__((ext_vector_type(8)));
typedef __bf16 bf16_4 __attribute__((ext_vector_type(4)));
typedef float f32_4 __attribute__((ext_vector_type(4)));

// ---------------- K1: zero counters + convert all weights ----------------
// Wl[K=128][NO], Wr[K=128][NO] fp32 -> Wt[2*NO][128] bf16 transposed concat

__device__ __forceinline__ void convw_one(const float* Wl, const float* Wr,
                                          __bf16* Wt, int NO, int i) {
    int k = i & 127;
    int n = i >> 7;
    const float* W = (n < NO) ? Wl : Wr;
    int nn = (n < NO) ? n : n - NO;
    Wt[i] = (__bf16)W[k * NO + nn];
}

__global__ void init_kernel(int* __restrict__ deg, unsigned long long* __restrict__ state,
                            int* __restrict__ vcounter, int* __restrict__ rowstart,
                            const float* __restrict__ Wl1, const float* __restrict__ Wr1, __bf16* __restrict__ Wt1,
                            const float* __restrict__ Wl2, const float* __restrict__ Wr2, __bf16* __restrict__ Wt2,
                            const float* __restrict__ Wl3, const float* __restrict__ Wr3, __bf16* __restrict__ Wt3) {
    int i = blockIdx.x * blockDim.x + threadIdx.x;
    if (i < NN) deg[i] = 0;
    if (i < NB) state[i] = 0ull;
    if (i == 0) { *vcounter = 0; rowstart[NN] = NE; }
    if (i < 32768)      convw_one(Wl1, Wr1, Wt1, 128, i);
    else if (i < 65536) convw_one(Wl2, Wr2, Wt2, 128, i - 32768);
    else if (i < 81920) convw_one(Wl3, Wr3, Wt3, 64, i - 65536);
}

// ---------------- K2: degree count ----------------

__global__ void deg_kernel(const int* __restrict__ dst, int* __restrict__ deg, int e) {
    int i = blockIdx.x * blockDim.x + threadIdx.x;
    if (i < e) atomicAdd(&deg[dst[i]], 1);
}

// ---------------- K3: single-pass decoupled-lookback scan ----------------

__global__ __launch_bounds__(1024)
void scan_kernel(const int* __restrict__ deg, int* __restrict__ rowstart,
                 int* __restrict__ cursor, float* __restrict__ inv,
                 unsigned long long* __restrict__ state, int* __restrict__ vcounter) {
    __shared__ int s[1024];
    __shared__ int s_vb, s_base;
    int tid = threadIdx.x;
    if (tid == 0) s_vb = atomicAdd(vcounter, 1);
    __syncthreads();
    int vb = s_vb;
    int i = vb * 1024 + tid;
    int v = (i < NN) ? deg[i] : 0;
    s[tid] = v;
    __syncthreads();
    for (int off = 1; off < 1024; off <<= 1) {
        int t = (tid >= off) ? s[tid - off] : 0;
        __syncthreads();
        s[tid] += t;
        __syncthreads();
    }
    int incl = s[tid];
    int agg = s[1023];
    if (tid == 0) {
        if (vb == 0) {
            atomicExch(&state[0], (2ull << 62) | (unsigned long long)(unsigned)agg);
            s_base = 0;
        } else {
            atomicExch(&state[vb], (1ull << 62) | (unsigned long long)(unsigned)agg);
            int base = 0;
            int p = vb - 1;
            while (p >= 0) {
                unsigned long long st;
                do { st = atomicAdd(&state[p], 0ull); } while ((st >> 62) == 0ull);
                base += (int)(unsigned)(st & 0xffffffffull);
                if ((st >> 62) == 2ull) break;
                --p;
            }
            atomicExch(&state[vb], (2ull << 62) | (unsigned long long)(unsigned)(base + agg));
            s_base = base;
        }
    }
    __syncthreads();
    int base = s_base;
    if (i < NN) {
        int excl = base + incl - v;
        rowstart[i] = excl;
        cursor[i] = excl;
        inv[i] = 1.0f / (float)max(v, 1);
    }
}

// ---------------- K4: CSR fill ----------------

__global__ void fill_kernel(const int* __restrict__ src, const int* __restrict__ dst,
                            int* __restrict__ cursor, int* __restrict__ col, int e) {
    int i = blockIdx.x * blockDim.x + threadIdx.x;
    if (i < e) {
        int p = atomicAdd(&cursor[dst[i]], 1);
        col[p] = src[i];
    }
}

// ---------------- fused layer kernel ----------------
// Computes A-tile (64 rows) in LDS, then C[64][Ncat] = A @ Bt^T, Ncat = 2*NO.
//   MODE 0: A row = x[node] (fp32 -> bf16)
//   MODE 1: A row = relu( inv[node] * sum_{u in N(node)} yprev[u] + zprev[node] )  (all bf16)
// cols 0..NO-1   -> Y bf16 (lin_l, no bias)
// cols NO..2NO-1 -> Z + bias (bf16, or fp32 if ZF32)
// B-fragments are read directly from global (weights are L2-resident, 64KB max).
// 256 threads = 4 waves; wave w owns cols [w*16*NFRAG, (w+1)*16*NFRAG).

template<int MODE, int ZF32, int NFRAG>
__global__ __launch_bounds__(256, 4)
void fused_layer(const void* __restrict__ Asrc, const __bf16* __restrict__ zprev,
                 const float* __restrict__ inv, const int* __restrict__ rowstart,
                 const int* __restrict__ col, const __bf16* __restrict__ Bt,
                 const float* __restrict__ bias, __bf16* __restrict__ Y,
                 void* __restrict__ Zp) {
    __shared__ __bf16 As[64 * 128];
    const int t = threadIdx.x;
    const int m0 = blockIdx.x * 64;
    const int NO = NFRAG * 32;  // NFRAG=4 -> NO=128, NFRAG=2 -> NO=64

    if (MODE == 0) {
        // stage x fp32 rows -> bf16 swizzled LDS; 64 rows x 16 chunks, 4 iters
        const float* x = (const float*)Asrc;
        #pragma unroll
        for (int it = 0; it < 4; ++it) {
            int r = (t >> 4) + it * 16;
            int c = t & 15;
            int gm = m0 + r;
            float4 lo = make_float4(0.f, 0.f, 0.f, 0.f), hi = lo;
            if (gm < NN) {
                lo = *(const float4*)&x[(size_t)gm * 128 + c * 8];
                hi = *(const float4*)&x[(size_t)gm * 128 + c * 8 + 4];
            }
            bf16_8 v;
            v[0] = (__bf16)lo.x; v[1] = (__bf16)lo.y; v[2] = (__bf16)lo.z; v[3] = (__bf16)lo.w;
            v[4] = (__bf16)hi.x; v[5] = (__bf16)hi.y; v[6] = (__bf16)hi.z; v[7] = (__bf16)hi.w;
            *(bf16_8*)&As[r * 128 + (c ^ (r & 7)) * 8] = v;
        }
    } else {
        // gather+finish: 16 groups of 16 lanes, 4 nodes per group
        const __bf16* yp = (const __bf16*)Asrc;
        int g = t >> 4, s = t & 15;
        #pragma unroll
        for (int ni = 0; ni < 4; ++ni) {
            int rl = g + ni * 16;        // local row 0..63
            int node = m0 + rl;
            bf16_8 o = {};
            if (node < NN) {
                int beg = rowstart[node], end = rowstart[node + 1];
                float iv = inv[node];
                float acc[8] = {};
                for (int e0 = beg; e0 < end; e0 += 8) {
                    int us[8];
                    #pragma unroll
                    for (int k = 0; k < 8; ++k) us[k] = (e0 + k < end) ? col[e0 + k] : -1;
                    bf16_8 vv[8];
                    #pragma unroll
                    for (int k = 0; k < 8; ++k) {
                        vv[k] = (bf16_8){};
                        if (us[k] >= 0) vv[k] = *(const bf16_8*)&yp[(size_t)us[k] * 128 + s * 8];
                    }
                    #pragma unroll
                    for (int j = 0; j < 8; ++j) {
                        float p0 = ((float)vv[0][j] + (float)vv[1][j]) + ((float)vv[2][j] + (float)vv[3][j]);
                        float p1 = ((float)vv[4][j] + (float)vv[5][j]) + ((float)vv[6][j] + (float)vv[7][j]);
                        acc[j] += p0 + p1;
                    }
                }
                bf16_8 zv = *(const bf16_8*)&zprev[(size_t)node * 128 + s * 8];
                #pragma unroll
                for (int j = 0; j < 8; ++j) {
                    float v = acc[j] * iv + (float)zv[j];
                    o[j] = (__bf16)fmaxf(v, 0.f);
                }
            }
            *(bf16_8*)&As[rl * 128 + (s ^ (rl & 7)) * 8] = o;
        }
    }
    __syncthreads();

    // MFMA: wave w covers all 64 rows x its 16*NFRAG-col strip
    const int w = t >> 6;
    const int wn = w * 16 * NFRAG;
    const int lane = t & 63;
    const int lr = lane & 15;
    const int kg = lane >> 4;

    f32_4 acc[4][NFRAG] = {};
    #pragma unroll
    for (int ks = 0; ks < 4; ++ks) {
        int kc16 = ks * 4 + kg;
        bf16_8 a[4], bb[NFRAG];
        #pragma unroll
        for (int mi = 0; mi < 4; ++mi) {
            int r = mi * 16 + lr;
            a[mi] = *(const bf16_8*)&As[r * 128 + (kc16 ^ (r & 7)) * 8];
        }
        #pragma unroll
        for (int ni = 0; ni < NFRAG; ++ni) {
            int n = wn + ni * 16 + lr;   // Bt row (= output col)
            bb[ni] = *(const bf16_8*)&Bt[(size_t)n * 128 + kc16 * 8];
        }
        #pragma unroll
        for (int mi = 0; mi < 4; ++mi)
            #pragma unroll
            for (int ni = 0; ni < NFRAG; ++ni)
                acc[mi][ni] = __builtin_amdgcn_mfma_f32_16x16x32_bf16(a[mi], bb[ni], acc[mi][ni], 0, 0, 0);
    }

    // epilogue: C/D layout col=lane&15, row=(lane>>4)*4+reg
    #pragma unroll
    for (int mi = 0; mi < 4; ++mi) {
        int gmb = m0 + mi * 16 + kg * 4;
        #pragma unroll
        for (int ni = 0; ni < NFRAG; ++ni) {
            int gc = wn + ni * 16 + lr;
            bool isY = gc < NO;
            float bv = 0.f;
            if (!isY) bv = bias[gc - NO];
            #pragma unroll
            for (int rr = 0; rr < 4; ++rr) {
                int gm = gmb + rr;
                if (gm < NN) {
                    float vv = acc[mi][ni][rr] + bv;
                    if (isY) Y[(size_t)gm * NO + gc] = (__bf16)vv;
                    else if (ZF32) ((float*)Zp)[(size_t)gm * NO + (gc - NO)] = vv;
                    else ((__bf16*)Zp)[(size_t)gm * NO + (gc - NO)] = (__bf16)vv;
                }
            }
        }
    }
}

// ---------------- final aggregation (layer 3 output, fp32) ----------------

__global__ __launch_bounds__(256)
void agg64_kernel(const __bf16* __restrict__ y, const float* __restrict__ z,
                  const int* __restrict__ rowstart, const int* __restrict__ col,
                  const float* __restrict__ inv, float* __restrict__ fout, int n) {
    int gid = blockIdx.x * 16 + (threadIdx.x >> 4);
    if (gid >= n) return;
    int s = threadIdx.x & 15;
    int beg = rowstart[gid], end = rowstart[gid + 1];
    float iv = inv[gid];
    float acc[4] = {};
    for (int e0 = beg; e0 < end; e0 += 8) {
        int us[8];
        #pragma unroll
        for (int k = 0; k < 8; ++k) us[k] = (e0 + k < end) ? col[e0 + k] : -1;
        bf16_4 vv[8];
        #pragma unroll
        for (int k = 0; k < 8; ++k) {
            vv[k] = (bf16_4){};
            if (us[k] >= 0) vv[k] = *(const bf16_4*)&y[(size_t)us[k] * 64 + s * 4];
        }
        #pragma unroll
        for (int j = 0; j < 4; ++j) {
            float p0 = ((float)vv[0][j] + (float)vv[1][j]) + ((float)vv[2][j] + (float)vv[3][j]);
            float p1 = ((float)vv[4][j] + (float)vv[5][j]) + ((float)vv[6][j] + (float)vv[7][j]);
            acc[j] += p0 + p1;
        }
    }
    float4 zv = *(const float4*)&z[(size_t)gid * 64 + s * 4];
    float4 o;
    o.x = acc[0] * iv + zv.x;
    o.y = acc[1] * iv + zv.y;
    o.z = acc[2] * iv + zv.z;
    o.w = acc[3] * iv + zv.w;
    *(float4*)&fout[(size_t)gid * 64 + s * 4] = o;
}

// ---------------- launch ----------------

extern "C" void kernel_launch(void* const* d_in, const int* in_sizes, int n_in,
                              void* d_out, int out_size, void* d_ws, size_t ws_size,
                              hipStream_t stream) {
    const float* x   = (const float*)d_in[0];
    const int*   ei  = (const int*)d_in[1];
    const int*   src = ei;
    const int*   dst = ei + NE;
    const float* Wl1 = (const float*)d_in[2];
    const float* Wr1 = (const float*)d_in[3];
    const float* b1  = (const float*)d_in[4];
    const float* Wl2 = (const float*)d_in[5];
    const float* Wr2 = (const float*)d_in[6];
    const float* b2  = (const float*)d_in[7];
    const float* Wl3 = (const float*)d_in[8];
    const float* Wr3 = (const float*)d_in[9];
    const float* b3  = (const float*)d_in[10];
    float* out = (float*)d_out;

    char* ws = (char*)d_ws;
    size_t off = 0;
    auto alloc = [&](size_t bytes) -> void* {
        void* p = ws + off;
        off += (bytes + 255) & ~(size_t)255;
        return p;
    };

    int*    deg      = (int*)alloc(NN * 4);
    int*    rowstart = (int*)alloc((NN + 1) * 4);
    int*    cursor   = (int*)alloc(NN * 4);
    int*    col      = (int*)alloc(NE * 4);
    float*  inv      = (float*)alloc(NN * 4);
    unsigned long long* state = (unsigned long long*)alloc(NB * 8);
    int*    vcounter = (int*)alloc(4);
    __bf16* y1       = (__bf16*)alloc((size_t)NN * 128 * 2);
    __bf16* z1       = (__bf16*)alloc((size_t)NN * 128 * 2);
    __bf16* y2       = (__bf16*)alloc((size_t)NN * 128 * 2);
    __bf16* z2       = (__bf16*)alloc((size_t)NN * 128 * 2);
    __bf16* y3       = (__bf16*)alloc((size_t)NN * 64 * 2);
    float*  zf       = (float*)alloc((size_t)NN * 64 * 4);
    __bf16* Wt1      = (__bf16*)alloc(256 * 128 * 2);
    __bf16* Wt2      = (__bf16*)alloc(256 * 128 * 2);
    __bf16* Wt3      = (__bf16*)alloc(128 * 128 * 2);

    init_kernel<<<320, 256, 0, stream>>>(deg, state, vcounter, rowstart,
                                         Wl1, Wr1, Wt1, Wl2, Wr2, Wt2, Wl3, Wr3, Wt3);
    deg_kernel<<<(NE + 255) / 256, 256, 0, stream>>>(dst, deg, NE);
    scan_kernel<<<NB, 1024, 0, stream>>>(deg, rowstart, cursor, inv, state, vcounter);
    fill_kernel<<<(NE + 255) / 256, 256, 0, stream>>>(src, dst, cursor, col, NE);

    int fblocks = (NN + 63) / 64;
    int aggBlocks = (NN + 15) / 16;

    // layer 1: A = x (fp32), outputs y1 (bf16) + z1 (bf16)
    fused_layer<0, 0, 4><<<fblocks, 256, 0, stream>>>(x, nullptr, nullptr, nullptr, nullptr,
                                                      Wt1, b1, y1, z1);
    // layer 2: A = relu(agg(y1)+z1), outputs y2 + z2
    fused_layer<1, 0, 4><<<fblocks, 256, 0, stream>>>(y1, z1, inv, rowstart, col,
                                                      Wt2, b2, y2, z2);
    // layer 3: A = relu(agg(y2)+z2), outputs y3 (bf16) + zf (fp32)
    fused_layer<1, 1, 2><<<fblocks, 256, 0, stream>>>(y2, z2, inv, rowstart, col,
                                                      Wt3, b3, y3, zf);
    // final: out = agg(y3)*inv + zf
    agg64_kernel<<<aggBlocks, 256, 0, stream>>>(y3, zf, rowstart, col, inv, out, NN);
}

// Round 9
// 191.900 us; speedup vs baseline: 1.7087x; 1.0262x over previous
//
#include <hip/hip_runtime.h>

#define NN 50000
#define NE 625000
#define NB 49  // ceil(NN/1024)
#define COLCAP 2048  // LDS col cache per 32-row tile (mean ~400, +58 sigma)

typedef __bf16 bf16_8 __attribute__((ext_vector_type(8)));
typedef __bf16 bf16_4 __attribute__((ext_vector_type(4)));
typedef float f32_4 __attribute__((ext_vector_type(4)));

// ---------------- K1: zero counters + convert all weights ----------------
// Wl[K=128][NO], Wr[K=128][NO] fp32 -> Wt[2*NO][128] bf16 transposed concat

__device__ __forceinline__ void convw_one(const float* Wl, const float* Wr,
                                          __bf16* Wt, int NO, int i) {
    int k = i & 127;
    int n = i >> 7;
    const float* W = (n < NO) ? Wl : Wr;
    int nn = (n < NO) ? n : n - NO;
    Wt[i] = (__bf16)W[k * NO + nn];
}

__global__ void init_kernel(int* __restrict__ deg, unsigned long long* __restrict__ state,
                            int* __restrict__ vcounter, int* __restrict__ rowstart,
                            const float* __restrict__ Wl1, const float* __restrict__ Wr1, __bf16* __restrict__ Wt1,
                            const float* __restrict__ Wl2, const float* __restrict__ Wr2, __bf16* __restrict__ Wt2,
                            const float* __restrict__ Wl3, const float* __restrict__ Wr3, __bf16* __restrict__ Wt3) {
    int i = blockIdx.x * blockDim.x + threadIdx.x;
    if (i < NN) deg[i] = 0;
    if (i < NB) state[i] = 0ull;
    if (i == 0) { *vcounter = 0; rowstart[NN] = NE; }
    if (i < 32768)      convw_one(Wl1, Wr1, Wt1, 128, i);
    else if (i < 65536) convw_one(Wl2, Wr2, Wt2, 128, i - 32768);
    else if (i < 81920) convw_one(Wl3, Wr3, Wt3, 64, i - 65536);
}

// ---------------- K2: degree count ----------------

__global__ void deg_kernel(const int* __restrict__ dst, int* __restrict__ deg, int e) {
    int i = blockIdx.x * blockDim.x + threadIdx.x;
    if (i < e) atomicAdd(&deg[dst[i]], 1);
}

// ---------------- K3: single-pass decoupled-lookback scan ----------------

__global__ __launch_bounds__(1024)
void scan_kernel(const int* __restrict__ deg, int* __restrict__ rowstart,
                 int* __restrict__ cursor, float* __restrict__ inv,
                 unsigned long long* __restrict__ state, int* __restrict__ vcounter) {
    __shared__ int s[1024];
    __shared__ int s_vb, s_base;
    int tid = threadIdx.x;
    if (tid == 0) s_vb = atomicAdd(vcounter, 1);
    __syncthreads();
    int vb = s_vb;
    int i = vb * 1024 + tid;
    int v = (i < NN) ? deg[i] : 0;
    s[tid] = v;
    __syncthreads();
    for (int off = 1; off < 1024; off <<= 1) {
        int t = (tid >= off) ? s[tid - off] : 0;
        __syncthreads();
        s[tid] += t;
        __syncthreads();
    }
    int incl = s[tid];
    int agg = s[1023];
    if (tid == 0) {
        if (vb == 0) {
            atomicExch(&state[0], (2ull << 62) | (unsigned long long)(unsigned)agg);
            s_base = 0;
        } else {
            atomicExch(&state[vb], (1ull << 62) | (unsigned long long)(unsigned)agg);
            int base = 0;
            int p = vb - 1;
            while (p >= 0) {
                unsigned long long st;
                do { st = atomicAdd(&state[p], 0ull); } while ((st >> 62) == 0ull);
                base += (int)(unsigned)(st & 0xffffffffull);
                if ((st >> 62) == 2ull) break;
                --p;
            }
            atomicExch(&state[vb], (2ull << 62) | (unsigned long long)(unsigned)(base + agg));
            s_base = base;
        }
    }
    __syncthreads();
    int base = s_base;
    if (i < NN) {
        int excl = base + incl - v;
        rowstart[i] = excl;
        cursor[i] = excl;
        inv[i] = 1.0f / (float)max(v, 1);
    }
}

// ---------------- K4: CSR fill ----------------

__global__ void fill_kernel(const int* __restrict__ src, const int* __restrict__ dst,
                            int* __restrict__ cursor, int* __restrict__ col, int e) {
    int i = blockIdx.x * blockDim.x + threadIdx.x;
    if (i < e) {
        int p = atomicAdd(&cursor[dst[i]], 1);
        col[p] = src[i];
    }
}

// ---------------- fused layer kernel (32-row tiles) ----------------
// A-tile (32 rows) in LDS, then C[32][Ncat] = A @ Bt^T, Ncat = 2*NO.
//   MODE 0: A row = x[node] (fp32 -> bf16)
//   MODE 1: A row = relu( inv[node] * sum_{u in N(node)} yprev[u] + zprev[node] )
// cols 0..NO-1   -> Y bf16 (lin_l, no bias);  cols NO..2NO-1 -> Z + bias
// col[] and rowstart[] for the tile staged in LDS (breaks dependent-load chain).
// 256 threads = 4 waves; wave w owns cols [w*16*NFRAG, (w+1)*16*NFRAG).

template<int MODE, int ZF32, int NFRAG>
__global__ __launch_bounds__(256, 6)
void fused_layer(const void* __restrict__ Asrc, const __bf16* __restrict__ zprev,
                 const float* __restrict__ inv, const int* __restrict__ rowstart,
                 const int* __restrict__ col, const __bf16* __restrict__ Bt,
                 const float* __restrict__ bias, __bf16* __restrict__ Y,
                 void* __restrict__ Zp) {
    __shared__ __bf16 As[32 * 128];
    __shared__ int s_row[33];
    __shared__ int colLds[COLCAP];
    const int t = threadIdx.x;
    const int m0 = blockIdx.x * 32;
    const int NO = NFRAG * 32;

    if (MODE == 0) {
        // stage x fp32 rows -> bf16 swizzled LDS; 32 rows x 16 chunks, 2 iters
        const float* x = (const float*)Asrc;
        #pragma unroll
        for (int it = 0; it < 2; ++it) {
            int r = (t >> 4) + it * 16;
            int c = t & 15;
            int gm = m0 + r;
            float4 lo = make_float4(0.f, 0.f, 0.f, 0.f), hi = lo;
            if (gm < NN) {
                lo = *(const float4*)&x[(size_t)gm * 128 + c * 8];
                hi = *(const float4*)&x[(size_t)gm * 128 + c * 8 + 4];
            }
            bf16_8 v;
            v[0] = (__bf16)lo.x; v[1] = (__bf16)lo.y; v[2] = (__bf16)lo.z; v[3] = (__bf16)lo.w;
            v[4] = (__bf16)hi.x; v[5] = (__bf16)hi.y; v[6] = (__bf16)hi.z; v[7] = (__bf16)hi.w;
            *(bf16_8*)&As[r * 128 + (c ^ (r & 7)) * 8] = v;
        }
    } else {
        // stage rowstart slice
        if (t < 33) {
            int idx = m0 + t;
            s_row[t] = rowstart[min(idx, NN)];
        }
        __syncthreads();
        const int beg0 = s_row[0];
        const int cnt = s_row[32] - beg0;
        // stage col slice (coalesced)
        int cmax = min(cnt, COLCAP);
        for (int i = t; i < cmax; i += 256) colLds[i] = col[beg0 + i];
        __syncthreads();

        // gather+finish: 16 groups of 16 lanes, 2 nodes per group
        const __bf16* yp = (const __bf16*)Asrc;
        int g = t >> 4, s = t & 15;
        #pragma unroll
        for (int ni = 0; ni < 2; ++ni) {
            int rl = g + ni * 16;        // local row 0..31
            int node = m0 + rl;
            bf16_8 o = {};
            if (node < NN) {
                int lbeg = s_row[rl] - beg0, lend = s_row[rl + 1] - beg0;
                float iv = inv[node];
                float acc[8] = {};
                for (int e0 = lbeg; e0 < lend; e0 += 8) {
                    int us[8];
                    #pragma unroll
                    for (int k = 0; k < 8; ++k) {
                        int e = e0 + k;
                        us[k] = -1;
                        if (e < lend) us[k] = (e < COLCAP) ? colLds[e] : col[beg0 + e];
                    }
                    bf16_8 vv[8];
                    #pragma unroll
                    for (int k = 0; k < 8; ++k) {
                        vv[k] = (bf16_8){};
                        if (us[k] >= 0) vv[k] = *(const bf16_8*)&yp[(size_t)us[k] * 128 + s * 8];
                    }
                    #pragma unroll
                    for (int j = 0; j < 8; ++j) {
                        float p0 = ((float)vv[0][j] + (float)vv[1][j]) + ((float)vv[2][j] + (float)vv[3][j]);
                        float p1 = ((float)vv[4][j] + (float)vv[5][j]) + ((float)vv[6][j] + (float)vv[7][j]);
                        acc[j] += p0 + p1;
                    }
                }
                bf16_8 zv = *(const bf16_8*)&zprev[(size_t)node * 128 + s * 8];
                #pragma unroll
                for (int j = 0; j < 8; ++j) {
                    float v = acc[j] * iv + (float)zv[j];
                    o[j] = (__bf16)fmaxf(v, 0.f);
                }
            }
            *(bf16_8*)&As[rl * 128 + (s ^ (rl & 7)) * 8] = o;
        }
    }
    __syncthreads();

    // MFMA: wave w covers 32 rows x its 16*NFRAG-col strip
    const int w = t >> 6;
    const int wn = w * 16 * NFRAG;
    const int lane = t & 63;
    const int lr = lane & 15;
    const int kg = lane >> 4;

    f32_4 acc[2][NFRAG] = {};
    #pragma unroll
    for (int ks = 0; ks < 4; ++ks) {
        int kc16 = ks * 4 + kg;
        bf16_8 a[2], bb[NFRAG];
        #pragma unroll
        for (int mi = 0; mi < 2; ++mi) {
            int r = mi * 16 + lr;
            a[mi] = *(const bf16_8*)&As[r * 128 + (kc16 ^ (r & 7)) * 8];
        }
        #pragma unroll
        for (int ni = 0; ni < NFRAG; ++ni) {
            int n = wn + ni * 16 + lr;   // Bt row (= output col)
            bb[ni] = *(const bf16_8*)&Bt[(size_t)n * 128 + kc16 * 8];
        }
        #pragma unroll
        for (int mi = 0; mi < 2; ++mi)
            #pragma unroll
            for (int ni = 0; ni < NFRAG; ++ni)
                acc[mi][ni] = __builtin_amdgcn_mfma_f32_16x16x32_bf16(a[mi], bb[ni], acc[mi][ni], 0, 0, 0);
    }

    // epilogue: C/D layout col=lane&15, row=(lane>>4)*4+reg
    #pragma unroll
    for (int mi = 0; mi < 2; ++mi) {
        int gmb = m0 + mi * 16 + kg * 4;
        #pragma unroll
        for (int ni = 0; ni < NFRAG; ++ni) {
            int gc = wn + ni * 16 + lr;
            bool isY = gc < NO;
            float bv = 0.f;
            if (!isY) bv = bias[gc - NO];
            #pragma unroll
            for (int rr = 0; rr < 4; ++rr) {
                int gm = gmb + rr;
                if (gm < NN) {
                    float vv = acc[mi][ni][rr] + bv;
                    if (isY) Y[(size_t)gm * NO + gc] = (__bf16)vv;
                    else if (ZF32) ((float*)Zp)[(size_t)gm * NO + (gc - NO)] = vv;
                    else ((__bf16*)Zp)[(size_t)gm * NO + (gc - NO)] = (__bf16)vv;
                }
            }
        }
    }
}

// ---------------- final aggregation (layer 3 output, fp32) ----------------

__global__ __launch_bounds__(256)
void agg64_kernel(const __bf16* __restrict__ y, const float* __restrict__ z,
                  const int* __restrict__ rowstart, const int* __restrict__ col,
                  const float* __restrict__ inv, float* __restrict__ fout, int n) {
    int gid = blockIdx.x * 16 + (threadIdx.x >> 4);
    if (gid >= n) return;
    int s = threadIdx.x & 15;
    int beg = rowstart[gid], end = rowstart[gid + 1];
    float iv = inv[gid];
    float acc[4] = {};
    for (int e0 = beg; e0 < end; e0 += 8) {
        int us[8];
        #pragma unroll
        for (int k = 0; k < 8; ++k) us[k] = (e0 + k < end) ? col[e0 + k] : -1;
        bf16_4 vv[8];
        #pragma unroll
        for (int k = 0; k < 8; ++k) {
            vv[k] = (bf16_4){};
            if (us[k] >= 0) vv[k] = *(const bf16_4*)&y[(size_t)us[k] * 64 + s * 4];
        }
        #pragma unroll
        for (int j = 0; j < 4; ++j) {
            float p0 = ((float)vv[0][j] + (float)vv[1][j]) + ((float)vv[2][j] + (float)vv[3][j]);
            float p1 = ((float)vv[4][j] + (float)vv[5][j]) + ((float)vv[6][j] + (float)vv[7][j]);
            acc[j] += p0 + p1;
        }
    }
    float4 zv = *(const float4*)&z[(size_t)gid * 64 + s * 4];
    float4 o;
    o.x = acc[0] * iv + zv.x;
    o.y = acc[1] * iv + zv.y;
    o.z = acc[2] * iv + zv.z;
    o.w = acc[3] * iv + zv.w;
    *(float4*)&fout[(size_t)gid * 64 + s * 4] = o;
}

// ---------------- launch ----------------

extern "C" void kernel_launch(void* const* d_in, const int* in_sizes, int n_in,
                              void* d_out, int out_size, void* d_ws, size_t ws_size,
                              hipStream_t stream) {
    const float* x   = (const float*)d_in[0];
    const int*   ei  = (const int*)d_in[1];
    const int*   src = ei;
    const int*   dst = ei + NE;
    const float* Wl1 = (const float*)d_in[2];
    const float* Wr1 = (const float*)d_in[3];
    const float* b1  = (const float*)d_in[4];
    const float* Wl2 = (const float*)d_in[5];
    const float* Wr2 = (const float*)d_in[6];
    const float* b2  = (const float*)d_in[7];
    const float* Wl3 = (const float*)d_in[8];
    const float* Wr3 = (const float*)d_in[9];
    const float* b3  = (const float*)d_in[10];
    float* out = (float*)d_out;

    char* ws = (char*)d_ws;
    size_t off = 0;
    auto alloc = [&](size_t bytes) -> void* {
        void* p = ws + off;
        off += (bytes + 255) & ~(size_t)255;
        return p;
    };

    int*    deg      = (int*)alloc(NN * 4);
    int*    rowstart = (int*)alloc((NN + 1) * 4);
    int*    cursor   = (int*)alloc(NN * 4);
    int*    col      = (int*)alloc(NE * 4);
    float*  inv      = (float*)alloc(NN * 4);
    unsigned long long* state = (unsigned long long*)alloc(NB * 8);
    int*    vcounter = (int*)alloc(4);
    __bf16* y1       = (__bf16*)alloc((size_t)NN * 128 * 2);
    __bf16* z1       = (__bf16*)alloc((size_t)NN * 128 * 2);
    __bf16* y2       = (__bf16*)alloc((size_t)NN * 128 * 2);
    __bf16* z2       = (__bf16*)alloc((size_t)NN * 128 * 2);
    __bf16* y3       = (__bf16*)alloc((size_t)NN * 64 * 2);
    float*  zf       = (float*)alloc((size_t)NN * 64 * 4);
    __bf16* Wt1      = (__bf16*)alloc(256 * 128 * 2);
    __bf16* Wt2      = (__bf16*)alloc(256 * 128 * 2);
    __bf16* Wt3      = (__bf16*)alloc(128 * 128 * 2);

    init_kernel<<<320, 256, 0, stream>>>(deg, state, vcounter, rowstart,
                                         Wl1, Wr1, Wt1, Wl2, Wr2, Wt2, Wl3, Wr3, Wt3);
    deg_kernel<<<(NE + 255) / 256, 256, 0, stream>>>(dst, deg, NE);
    scan_kernel<<<NB, 1024, 0, stream>>>(deg, rowstart, cursor, inv, state, vcounter);
    fill_kernel<<<(NE + 255) / 256, 256, 0, stream>>>(src, dst, cursor, col, NE);

    int fblocks = (NN + 31) / 32;
    int aggBlocks = (NN + 15) / 16;

    // layer 1: A = x (fp32), outputs y1 (bf16) + z1 (bf16)
    fused_layer<0, 0, 4><<<fblocks, 256, 0, stream>>>(x, nullptr, nullptr, nullptr, nullptr,
                                                      Wt1, b1, y1, z1);
    // layer 2: A = relu(agg(y1)+z1), outputs y2 + z2
    fused_layer<1, 0, 4><<<fblocks, 256, 0, stream>>>(y1, z1, inv, rowstart, col,
                                                      Wt2, b2, y2, z2);
    // layer 3: A = relu(agg(y2)+z2), outputs y3 (bf16) + zf (fp32)
    fused_layer<1, 1, 2><<<fblocks, 256, 0, stream>>>(y2, z2, inv, rowstart, col,
                                                      Wt3, b3, y3, zf);
    // final: out = agg(y3)*inv + zf
    agg64_kernel<<<aggBlocks, 256, 0, stream>>>(y3, zf, rowstart, col, inv, out, NN);
}

// Round 10
// 189.670 us; speedup vs baseline: 1.7288x; 1.0118x over previous
//
#include <hip/hip_runtime.h>

#define NN 50000
#define NE 625000
#define NB 49  // ceil(NN/1024)
#define COLCAP 2048  // LDS col cache per 32-row tile (mean ~400)

typedef __bf16 bf16_8 __attribute__((ext_vector_type(8)));
typedef __bf16 bf16_4 __attribute__((ext_vector_type(4)));
typedef float f32_4 __attribute__((ext_vector_type(4)));
typedef float f32_2 __attribute__((ext_vector_type(2)));

// ---------------- K1: zero counters + convert all weights ----------------

__device__ __forceinline__ void convw_one(const float* Wl, const float* Wr,
                                          __bf16* Wt, int NO, int i) {
    int k = i & 127;
    int n = i >> 7;
    const float* W = (n < NO) ? Wl : Wr;
    int nn = (n < NO) ? n : n - NO;
    Wt[i] = (__bf16)W[k * NO + nn];
}

__global__ void init_kernel(int* __restrict__ deg, unsigned long long* __restrict__ state,
                            int* __restrict__ vcounter, int* __restrict__ rowstart,
                            const float* __restrict__ Wl1, const float* __restrict__ Wr1, __bf16* __restrict__ Wt1,
                            const float* __restrict__ Wl2, const float* __restrict__ Wr2, __bf16* __restrict__ Wt2,
                            const float* __restrict__ Wl3, const float* __restrict__ Wr3, __bf16* __restrict__ Wt3) {
    int i = blockIdx.x * blockDim.x + threadIdx.x;
    if (i < NN) deg[i] = 0;
    if (i < NB) state[i] = 0ull;
    if (i == 0) { *vcounter = 0; rowstart[NN] = NE; }
    if (i < 32768)      convw_one(Wl1, Wr1, Wt1, 128, i);
    else if (i < 65536) convw_one(Wl2, Wr2, Wt2, 128, i - 32768);
    else if (i < 81920) convw_one(Wl3, Wr3, Wt3, 64, i - 65536);
}

// ---------------- K2: degree count ----------------

__global__ void deg_kernel(const int* __restrict__ dst, int* __restrict__ deg, int e) {
    int i = blockIdx.x * blockDim.x + threadIdx.x;
    if (i < e) atomicAdd(&deg[dst[i]], 1);
}

// ---------------- K3: single-pass decoupled-lookback scan ----------------

__global__ __launch_bounds__(1024)
void scan_kernel(const int* __restrict__ deg, int* __restrict__ rowstart,
                 int* __restrict__ cursor, float* __restrict__ inv,
                 unsigned long long* __restrict__ state, int* __restrict__ vcounter) {
    __shared__ int s[1024];
    __shared__ int s_vb, s_base;
    int tid = threadIdx.x;
    if (tid == 0) s_vb = atomicAdd(vcounter, 1);
    __syncthreads();
    int vb = s_vb;
    int i = vb * 1024 + tid;
    int v = (i < NN) ? deg[i] : 0;
    s[tid] = v;
    __syncthreads();
    for (int off = 1; off < 1024; off <<= 1) {
        int t = (tid >= off) ? s[tid - off] : 0;
        __syncthreads();
        s[tid] += t;
        __syncthreads();
    }
    int incl = s[tid];
    int agg = s[1023];
    if (tid == 0) {
        if (vb == 0) {
            atomicExch(&state[0], (2ull << 62) | (unsigned long long)(unsigned)agg);
            s_base = 0;
        } else {
            atomicExch(&state[vb], (1ull << 62) | (unsigned long long)(unsigned)agg);
            int base = 0;
            int p = vb - 1;
            while (p >= 0) {
                unsigned long long st;
                do { st = atomicAdd(&state[p], 0ull); } while ((st >> 62) == 0ull);
                base += (int)(unsigned)(st & 0xffffffffull);
                if ((st >> 62) == 2ull) break;
                --p;
            }
            atomicExch(&state[vb], (2ull << 62) | (unsigned long long)(unsigned)(base + agg));
            s_base = base;
        }
    }
    __syncthreads();
    int base = s_base;
    if (i < NN) {
        int excl = base + incl - v;
        rowstart[i] = excl;
        cursor[i] = excl;
        inv[i] = 1.0f / (float)max(v, 1);
    }
}

// ---------------- K4: CSR fill ----------------

__global__ void fill_kernel(const int* __restrict__ src, const int* __restrict__ dst,
                            int* __restrict__ cursor, int* __restrict__ col, int e) {
    int i = blockIdx.x * blockDim.x + threadIdx.x;
    if (i < e) {
        int p = atomicAdd(&cursor[dst[i]], 1);
        col[p] = src[i];
    }
}

// ---------------- fused layer kernel (32-row tiles) ----------------
// A-tile (32 rows) in LDS, then C[32][Ncat] = A @ Bt^T, Ncat = 2*NO.
//   MODE 0: A row = x[node] (fp32 -> bf16)
//   MODE 1: A row = relu( inv[node]*sum_{u in N(node)} yprev_f8[u] + zprev[node] )
//           yprev is fp8 e4m3 [node][128], decoded via HW cvt_pk_f32_fp8.
// Y output: fp8 (YF8=1, HW cvt_pk_fp8_f32) or bf16.  Z: bf16 or fp32.
// 256 threads = 4 waves; wave w owns cols [w*16*NFRAG, (w+1)*16*NFRAG).

template<int MODE, int ZF32, int NFRAG, int YF8>
__global__ __launch_bounds__(256, 6)
void fused_layer(const void* __restrict__ Asrc, const __bf16* __restrict__ zprev,
                 const float* __restrict__ inv, const int* __restrict__ rowstart,
                 const int* __restrict__ col, const __bf16* __restrict__ Bt,
                 const float* __restrict__ bias, void* __restrict__ Yp,
                 void* __restrict__ Zp) {
    __shared__ __bf16 As[32 * 128];
    __shared__ int s_row[33];
    __shared__ int colLds[COLCAP];
    const int t = threadIdx.x;
    const int m0 = blockIdx.x * 32;
    const int NO = NFRAG * 32;

    if (MODE == 0) {
        const float* x = (const float*)Asrc;
        #pragma unroll
        for (int it = 0; it < 2; ++it) {
            int r = (t >> 4) + it * 16;
            int c = t & 15;
            int gm = m0 + r;
            float4 lo = make_float4(0.f, 0.f, 0.f, 0.f), hi = lo;
            if (gm < NN) {
                lo = *(const float4*)&x[(size_t)gm * 128 + c * 8];
                hi = *(const float4*)&x[(size_t)gm * 128 + c * 8 + 4];
            }
            bf16_8 v;
            v[0] = (__bf16)lo.x; v[1] = (__bf16)lo.y; v[2] = (__bf16)lo.z; v[3] = (__bf16)lo.w;
            v[4] = (__bf16)hi.x; v[5] = (__bf16)hi.y; v[6] = (__bf16)hi.z; v[7] = (__bf16)hi.w;
            *(bf16_8*)&As[r * 128 + (c ^ (r & 7)) * 8] = v;
        }
    } else {
        if (t < 33) {
            int idx = m0 + t;
            s_row[t] = rowstart[min(idx, NN)];
        }
        __syncthreads();
        const int beg0 = s_row[0];
        const int cnt = s_row[32] - beg0;
        int cmax = min(cnt, COLCAP);
        for (int i = t; i < cmax; i += 256) colLds[i] = col[beg0 + i];
        __syncthreads();

        // gather+finish: 16 groups of 16 lanes, 2 nodes per group, fp8 rows (128B)
        const unsigned char* yp = (const unsigned char*)Asrc;
        int g = t >> 4, s = t & 15;
        #pragma unroll
        for (int ni = 0; ni < 2; ++ni) {
            int rl = g + ni * 16;
            int node = m0 + rl;
            bf16_8 o = {};
            if (node < NN) {
                int lbeg = s_row[rl] - beg0, lend = s_row[rl + 1] - beg0;
                float iv = inv[node];
                float acc[8] = {};
                for (int e0 = lbeg; e0 < lend; e0 += 8) {
                    int us[8];
                    #pragma unroll
                    for (int k = 0; k < 8; ++k) {
                        int e = e0 + k;
                        us[k] = -1;
                        if (e < lend) us[k] = (e < COLCAP) ? colLds[e] : col[beg0 + e];
                    }
                    uint2 vv[8];
                    #pragma unroll
                    for (int k = 0; k < 8; ++k) {
                        vv[k] = make_uint2(0u, 0u);  // fp8 0x00 == 0.0f
                        if (us[k] >= 0) vv[k] = *(const uint2*)&yp[(size_t)us[k] * 128 + s * 8];
                    }
                    #pragma unroll
                    for (int k = 0; k < 8; ++k) {
                        f32_2 a0 = __builtin_amdgcn_cvt_pk_f32_fp8(vv[k].x, false);
                        f32_2 a1 = __builtin_amdgcn_cvt_pk_f32_fp8(vv[k].x, true);
                        f32_2 a2 = __builtin_amdgcn_cvt_pk_f32_fp8(vv[k].y, false);
                        f32_2 a3 = __builtin_amdgcn_cvt_pk_f32_fp8(vv[k].y, true);
                        acc[0] += a0.x; acc[1] += a0.y;
                        acc[2] += a1.x; acc[3] += a1.y;
                        acc[4] += a2.x; acc[5] += a2.y;
                        acc[6] += a3.x; acc[7] += a3.y;
                    }
                }
                bf16_8 zv = *(const bf16_8*)&zprev[(size_t)node * 128 + s * 8];
                #pragma unroll
                for (int j = 0; j < 8; ++j) {
                    float v = acc[j] * iv + (float)zv[j];
                    o[j] = (__bf16)fmaxf(v, 0.f);
                }
            }
            *(bf16_8*)&As[rl * 128 + (s ^ (rl & 7)) * 8] = o;
        }
    }
    __syncthreads();

    // MFMA: wave w covers 32 rows x its 16*NFRAG-col strip
    const int w = t >> 6;
    const int wn = w * 16 * NFRAG;
    const int lane = t & 63;
    const int lr = lane & 15;
    const int kg = lane >> 4;

    f32_4 acc[2][NFRAG] = {};
    #pragma unroll
    for (int ks = 0; ks < 4; ++ks) {
        int kc16 = ks * 4 + kg;
        bf16_8 a[2], bb[NFRAG];
        #pragma unroll
        for (int mi = 0; mi < 2; ++mi) {
            int r = mi * 16 + lr;
            a[mi] = *(const bf16_8*)&As[r * 128 + (kc16 ^ (r & 7)) * 8];
        }
        #pragma unroll
        for (int ni = 0; ni < NFRAG; ++ni) {
            int n = wn + ni * 16 + lr;
            bb[ni] = *(const bf16_8*)&Bt[(size_t)n * 128 + kc16 * 8];
        }
        #pragma unroll
        for (int mi = 0; mi < 2; ++mi)
            #pragma unroll
            for (int ni = 0; ni < NFRAG; ++ni)
                acc[mi][ni] = __builtin_amdgcn_mfma_f32_16x16x32_bf16(a[mi], bb[ni], acc[mi][ni], 0, 0, 0);
    }

    // epilogue: C/D layout col=lane&15, row=(lane>>4)*4+reg
    #pragma unroll
    for (int mi = 0; mi < 2; ++mi) {
        int gmb = m0 + mi * 16 + kg * 4;
        #pragma unroll
        for (int ni = 0; ni < NFRAG; ++ni) {
            int gc = wn + ni * 16 + lr;
            bool isY = gc < NO;
            float bv = 0.f;
            if (!isY) bv = bias[gc - NO];
            #pragma unroll
            for (int rr = 0; rr < 4; ++rr) {
                int gm = gmb + rr;
                if (gm < NN) {
                    float vv = acc[mi][ni][rr] + bv;
                    if (isY) {
                        if (YF8) {
                            int pk = __builtin_amdgcn_cvt_pk_fp8_f32(vv, vv, 0, false);
                            ((unsigned char*)Yp)[(size_t)gm * NO + gc] = (unsigned char)(pk & 0xff);
                        } else {
                            ((__bf16*)Yp)[(size_t)gm * NO + gc] = (__bf16)vv;
                        }
                    }
                    else if (ZF32) ((float*)Zp)[(size_t)gm * NO + (gc - NO)] = vv;
                    else ((__bf16*)Zp)[(size_t)gm * NO + (gc - NO)] = (__bf16)vv;
                }
            }
        }
    }
}

// ---------------- final aggregation (layer 3 output, fp32) ----------------

__global__ __launch_bounds__(256)
void agg64_kernel(const __bf16* __restrict__ y, const float* __restrict__ z,
                  const int* __restrict__ rowstart, const int* __restrict__ col,
                  const float* __restrict__ inv, float* __restrict__ fout, int n) {
    int gid = blockIdx.x * 16 + (threadIdx.x >> 4);
    if (gid >= n) return;
    int s = threadIdx.x & 15;
    int beg = rowstart[gid], end = rowstart[gid + 1];
    float iv = inv[gid];
    float acc[4] = {};
    for (int e0 = beg; e0 < end; e0 += 8) {
        int us[8];
        #pragma unroll
        for (int k = 0; k < 8; ++k) us[k] = (e0 + k < end) ? col[e0 + k] : -1;
        bf16_4 vv[8];
        #pragma unroll
        for (int k = 0; k < 8; ++k) {
            vv[k] = (bf16_4){};
            if (us[k] >= 0) vv[k] = *(const bf16_4*)&y[(size_t)us[k] * 64 + s * 4];
        }
        #pragma unroll
        for (int j = 0; j < 4; ++j) {
            float p0 = ((float)vv[0][j] + (float)vv[1][j]) + ((float)vv[2][j] + (float)vv[3][j]);
            float p1 = ((float)vv[4][j] + (float)vv[5][j]) + ((float)vv[6][j] + (float)vv[7][j]);
            acc[j] += p0 + p1;
        }
    }
    float4 zv = *(const float4*)&z[(size_t)gid * 64 + s * 4];
    float4 o;
    o.x = acc[0] * iv + zv.x;
    o.y = acc[1] * iv + zv.y;
    o.z = acc[2] * iv + zv.z;
    o.w = acc[3] * iv + zv.w;
    *(float4*)&fout[(size_t)gid * 64 + s * 4] = o;
}

// ---------------- launch ----------------

extern "C" void kernel_launch(void* const* d_in, const int* in_sizes, int n_in,
                              void* d_out, int out_size, void* d_ws, size_t ws_size,
                              hipStream_t stream) {
    const float* x   = (const float*)d_in[0];
    const int*   ei  = (const int*)d_in[1];
    const int*   src = ei;
    const int*   dst = ei + NE;
    const float* Wl1 = (const float*)d_in[2];
    const float* Wr1 = (const float*)d_in[3];
    const float* b1  = (const float*)d_in[4];
    const float* Wl2 = (const float*)d_in[5];
    const float* Wr2 = (const float*)d_in[6];
    const float* b2  = (const float*)d_in[7];
    const float* Wl3 = (const float*)d_in[8];
    const float* Wr3 = (const float*)d_in[9];
    const float* b3  = (const float*)d_in[10];
    float* out = (float*)d_out;

    char* ws = (char*)d_ws;
    size_t off = 0;
    auto alloc = [&](size_t bytes) -> void* {
        void* p = ws + off;
        off += (bytes + 255) & ~(size_t)255;
        return p;
    };

    int*    deg      = (int*)alloc(NN * 4);
    int*    rowstart = (int*)alloc((NN + 1) * 4);
    int*    cursor   = (int*)alloc(NN * 4);
    int*    col      = (int*)alloc(NE * 4);
    float*  inv      = (float*)alloc(NN * 4);
    unsigned long long* state = (unsigned long long*)alloc(NB * 8);
    int*    vcounter = (int*)alloc(4);
    unsigned char* y1 = (unsigned char*)alloc((size_t)NN * 128);
    __bf16* z1       = (__bf16*)alloc((size_t)NN * 128 * 2);
    unsigned char* y2 = (unsigned char*)alloc((size_t)NN * 128);
    __bf16* z2       = (__bf16*)alloc((size_t)NN * 128 * 2);
    __bf16* y3       = (__bf16*)alloc((size_t)NN * 64 * 2);
    float*  zf       = (float*)alloc((size_t)NN * 64 * 4);
    __bf16* Wt1      = (__bf16*)alloc(256 * 128 * 2);
    __bf16* Wt2      = (__bf16*)alloc(256 * 128 * 2);
    __bf16* Wt3      = (__bf16*)alloc(128 * 128 * 2);

    init_kernel<<<320, 256, 0, stream>>>(deg, state, vcounter, rowstart,
                                         Wl1, Wr1, Wt1, Wl2, Wr2, Wt2, Wl3, Wr3, Wt3);
    deg_kernel<<<(NE + 255) / 256, 256, 0, stream>>>(dst, deg, NE);
    scan_kernel<<<NB, 1024, 0, stream>>>(deg, rowstart, cursor, inv, state, vcounter);
    fill_kernel<<<(NE + 255) / 256, 256, 0, stream>>>(src, dst, cursor, col, NE);

    int fblocks = (NN + 31) / 32;
    int aggBlocks = (NN + 15) / 16;

    // layer 1: A = x (fp32), outputs y1 (fp8) + z1 (bf16)
    fused_layer<0, 0, 4, 1><<<fblocks, 256, 0, stream>>>(x, nullptr, nullptr, nullptr, nullptr,
                                                         Wt1, b1, y1, z1);
    // layer 2: A = relu(agg(y1)+z1), outputs y2 (fp8) + z2 (bf16)
    fused_layer<1, 0, 4, 1><<<fblocks, 256, 0, stream>>>(y1, z1, inv, rowstart, col,
                                                         Wt2, b2, y2, z2);
    // layer 3: A = relu(agg(y2)+z2), outputs y3 (bf16) + zf (fp32)
    fused_layer<1, 1, 2, 0><<<fblocks, 256, 0, stream>>>(y2, z2, inv, rowstart, col,
                                                         Wt3, b3, y3, zf);
    // final: out = agg(y3)*inv + zf
    agg64_kernel<<<aggBlocks, 256, 0, stream>>>(y3, zf, rowstart, col, inv, out, NN);
}